// Round 8
// baseline (145.571 us; speedup 1.0000x reference)
//
#include <hip/hip_runtime.h>
#include <hip/hip_bf16.h>
#include <cstdint>
#include <cstddef>

#define BN_EPS 1e-5f

typedef float f32x4_t __attribute__((ext_vector_type(4)));
typedef __bf16 bf16x8_t __attribute__((ext_vector_type(8)));

__device__ __forceinline__ unsigned short f2bf(float f) {
    __hip_bfloat16 h = __float2bfloat16(f);
    return __builtin_bit_cast(unsigned short, h);
}

// async global->LDS, 16B/lane; LDS dest is wave-uniform base + lane*16.
__device__ __forceinline__ void gld_lds16(void* lds, const void* gp) {
#if __has_builtin(__builtin_amdgcn_global_load_lds)
    __builtin_amdgcn_global_load_lds(
        (const __attribute__((address_space(1))) unsigned int*)gp,
        (__attribute__((address_space(3))) unsigned int*)lds, 16, 0, 0);
#else
    *(uint4*)lds = *(const uint4*)gp;
#endif
}

// ---------------- ws layout ----------------
// kpb    : bf16  [512 col=t*64+o][64 c]   32768 us
// escale : float [B][T][N]                65536 f
// bns    : float sum[64]+sumsq[64]+cnt    136 f (cnt @ [128] as uint)
// rowsum : float [B][N]                   8192 f
// He2    : float [4 part][B*N][64]        2097152 f  (8 MB)
// G      : bf16  [B][N][N]                8388608 us (16 MB)
// bmatT  : bf16  [B][512 col][N(m)]       4194304 us (8 MB)

// K1: blocks 0..1023: G[b][row][*] bf16 + rowsum (column octet in registers).
//     blocks 1024..1151: repack k_tensor -> kpb bf16 [t*64+o][c]; zero bns+cnt.
__global__ __launch_bounds__(256) void k_g(const float* __restrict__ points,
                                           const float* __restrict__ ktens,
                                           unsigned short* __restrict__ G,
                                           float* __restrict__ rowsum,
                                           unsigned short* __restrict__ kpb,
                                           float* __restrict__ bns) {
    __shared__ float praw[3072];
    __shared__ float px[1024], py[1024], pz[1024], hq[1024];
    __shared__ float rs[8];

    const int tid = threadIdx.x;
    if (blockIdx.x >= 1024) {             // pack branch (block-uniform)
        const int i = (blockIdx.x - 1024) * 256 + tid;   // i = (t*64+o)*64 + c
        const int t = i >> 12, o = (i >> 6) & 63, c = i & 63;
        kpb[i] = f2bf(ktens[(o * 64 + c) * 8 + t]);
        if (blockIdx.x == 1024 && tid < 136) bns[tid] = 0.f;   // stats + counter
        return;
    }

    const int b  = blockIdx.x & 7;               // XCD swizzle
    const int n0 = (blockIdx.x >> 3) * 8;

    for (int i = tid; i < 3072; i += 256) praw[i] = points[b * 3072 + i];
    if (tid < 8) rs[tid] = 0.f;
    __syncthreads();
    for (int n = tid; n < 1024; n += 256) {
        float x = praw[n * 3], y = praw[n * 3 + 1], z = praw[n * 3 + 2];
        px[n] = x; py[n] = y; pz[n] = z;
        hq[n] = -0.5f * (x * x + y * y + z * z);
    }
    __syncthreads();

    const int rhalf = tid >> 7;                  // 0/1: which row of the pair
    const int c0 = (tid & 127) * 8;              // column octet
    float vx[8], vy[8], vz[8], vh[8];
    *(float4*)&vx[0] = *(const float4*)&px[c0];
    *(float4*)&vx[4] = *(const float4*)&px[c0 + 4];
    *(float4*)&vy[0] = *(const float4*)&py[c0];
    *(float4*)&vy[4] = *(const float4*)&py[c0 + 4];
    *(float4*)&vz[0] = *(const float4*)&pz[c0];
    *(float4*)&vz[4] = *(const float4*)&pz[c0 + 4];
    *(float4*)&vh[0] = *(const float4*)&hq[c0];
    *(float4*)&vh[4] = *(const float4*)&hq[c0 + 4];

    unsigned short* gb = G + ((size_t)b << 20);

    #pragma unroll
    for (int u = 0; u < 4; ++u) {
        const int rl = u * 2 + rhalf;
        const int row = n0 + rl;
        const float rx = px[row], ry = py[row], rz = pz[row], hr = hq[row];
        unsigned short us[8];
        float ssum = 0.f;
        #pragma unroll
        for (int j = 0; j < 8; ++j) {
            float e = __expf(hr + vh[j] + rx * vx[j] + ry * vy[j] + rz * vz[j]);
            ssum += e;
            us[j] = f2bf(e);
        }
        uint4 pk;
        pk.x = us[0] | ((unsigned int)us[1] << 16);
        pk.y = us[2] | ((unsigned int)us[3] << 16);
        pk.z = us[4] | ((unsigned int)us[5] << 16);
        pk.w = us[6] | ((unsigned int)us[7] << 16);
        *(uint4*)(gb + (size_t)row * 1024 + c0) = pk;
        #pragma unroll
        for (int m = 32; m; m >>= 1) ssum += __shfl_xor(ssum, m, 64);
        if ((tid & 63) == 0) atomicAdd(&rs[rl], ssum);
    }
    __syncthreads();
    if (tid < 8) rowsum[b * 1024 + n0 + tid] = rs[tid];
}

// K2: MFMA prep GEMM: bmat[m][col] = (sfac[t,m]/rowsum[m]) * sum_c funcs[m,c]*kpb[col,c]
// grid 256 = b(8) x mt(8,128 rows) x ct(4,128 cols); 4 waves; K=64; also escale.
__global__ __launch_bounds__(256) void k_prep(const float* __restrict__ points,
                                              const float* __restrict__ trans,
                                              const float* __restrict__ funcs,
                                              const unsigned short* __restrict__ kpb,
                                              const float* __restrict__ rowsum,
                                              unsigned short* __restrict__ bmatT,
                                              float* __restrict__ escale) {
    __shared__ unsigned short Asm[128 * 72];   // [m][c] bf16, stride 72
    __shared__ unsigned short Bsm[128 * 72];   // [col][c] bf16, stride 72
    __shared__ float sfacl[256];               // [tloc(2)][m(128)]

    const int b  = blockIdx.x & 7;
    const int mt = (blockIdx.x >> 3) & 7;
    const int ct = blockIdx.x >> 6;            // 0..3 (t-pair)
    const int m0 = mt * 128;

    const int tid  = threadIdx.x;
    const int wave = tid >> 6, lane = tid & 63;
    const int wr = wave >> 1, wc = wave & 1;
    const int fr = lane & 15, quad = lane >> 4;

    // sfac + escale (global reads only; no LDS dependency)
    {
        const int tloc = tid >> 7, m = tid & 127;
        const int t = ct * 2 + tloc;
        const float tx = trans[b * 24 + t * 3], ty = trans[b * 24 + t * 3 + 1],
                    tz = trans[b * 24 + t * 3 + 2];
        const float* pp = &points[(size_t)(b * 1024 + m0 + m) * 3];
        const float ptd = pp[0] * tx + pp[1] * ty + pp[2] * tz;
        const float tsq = tx * tx + ty * ty + tz * tz;
        const float rsv = rowsum[b * 1024 + m0 + m];
        sfacl[tloc * 128 + m] = __expf(-ptd - 0.5f * tsq) / rsv;
        escale[(size_t)(b * 8 + t) * 1024 + m0 + m] = __expf(ptd);
    }
    // stage A: funcs fp32 -> bf16 LDS [m][c]
    #pragma unroll
    for (int rep = 0; rep < 2; ++rep) {
        const int m = rep * 64 + (tid >> 2);
        const int c16 = (tid & 3) * 16;
        const float* fp = &funcs[((size_t)(b * 1024) + m0 + m) * 64 + c16];
        float4 f0 = *(const float4*)fp, f1 = *(const float4*)(fp + 4);
        float4 f2 = *(const float4*)(fp + 8), f3 = *(const float4*)(fp + 12);
        uint4 p0, p1;
        p0.x = f2bf(f0.x) | ((unsigned)f2bf(f0.y) << 16);
        p0.y = f2bf(f0.z) | ((unsigned)f2bf(f0.w) << 16);
        p0.z = f2bf(f1.x) | ((unsigned)f2bf(f1.y) << 16);
        p0.w = f2bf(f1.z) | ((unsigned)f2bf(f1.w) << 16);
        p1.x = f2bf(f2.x) | ((unsigned)f2bf(f2.y) << 16);
        p1.y = f2bf(f2.z) | ((unsigned)f2bf(f2.w) << 16);
        p1.z = f2bf(f3.x) | ((unsigned)f2bf(f3.y) << 16);
        p1.w = f2bf(f3.z) | ((unsigned)f2bf(f3.w) << 16);
        *(uint4*)&Asm[m * 72 + c16] = p0;
        *(uint4*)&Asm[m * 72 + c16 + 8] = p1;
    }
    // stage B: kpb bf16 -> LDS [col][c]
    #pragma unroll
    for (int rep = 0; rep < 4; ++rep) {
        const int col = rep * 32 + (tid >> 3);
        const int c8 = (tid & 7) * 8;
        uint4 v = *(const uint4*)&kpb[(size_t)(ct * 128 + col) * 64 + c8];
        *(uint4*)&Bsm[col * 72 + c8] = v;
    }
    __syncthreads();

    f32x4_t acc[4][4];
    #pragma unroll
    for (int i = 0; i < 4; ++i)
        #pragma unroll
        for (int j = 0; j < 4; ++j) acc[i][j] = f32x4_t{0.f, 0.f, 0.f, 0.f};

    #pragma unroll
    for (int s = 0; s < 2; ++s) {
        uint4 afr[4], bfr[4];
        #pragma unroll
        for (int i = 0; i < 4; ++i)
            afr[i] = *(const uint4*)&Asm[(wr * 64 + i * 16 + fr) * 72 + s * 32 + quad * 8];
        #pragma unroll
        for (int j = 0; j < 4; ++j)
            bfr[j] = *(const uint4*)&Bsm[(wc * 64 + j * 16 + fr) * 72 + s * 32 + quad * 8];
        #pragma unroll
        for (int i = 0; i < 4; ++i)
            #pragma unroll
            for (int j = 0; j < 4; ++j)
                acc[i][j] = __builtin_amdgcn_mfma_f32_16x16x32_bf16(
                    __builtin_bit_cast(bf16x8_t, afr[i]),
                    __builtin_bit_cast(bf16x8_t, bfr[j]),
                    acc[i][j], 0, 0, 0);
    }

    // epilogue: scale and pack 4 consecutive m per lane -> bmatT[b][col][m]
    #pragma unroll
    for (int i = 0; i < 4; ++i) {
        #pragma unroll
        for (int j = 0; j < 4; ++j) {
            const int colg = ct * 128 + wc * 64 + j * 16 + fr;
            ushort4 pk;
            {
                const int mb = wr * 64 + i * 16 + quad * 4;
                pk.x = f2bf(acc[i][j][0] * sfacl[wc * 128 + mb + 0]);
                pk.y = f2bf(acc[i][j][1] * sfacl[wc * 128 + mb + 1]);
                pk.z = f2bf(acc[i][j][2] * sfacl[wc * 128 + mb + 2]);
                pk.w = f2bf(acc[i][j][3] * sfacl[wc * 128 + mb + 3]);
                *(ushort4*)&bmatT[(size_t)(b * 512 + colg) * 1024 + m0 + mb] = pk;
            }
        }
    }
}

// K3: bf16 GEMM, BK=64 (4 chunks), global_load_lds + XOR-8 k-group swizzle.
// grid 1024 = b(8) x rt(8) x [og(4) x kh(4)]; 4 waves; 128x128 tile, K/4=256.
// NOTE: no min-waves launch bound — forcing 4 waves/EU capped VGPR at 128 and
// spilled the 64-acc + 32-frag working set into scratch (R7 regression).
__global__ __launch_bounds__(256) void k_gemm(const unsigned short* __restrict__ G,
                                              const unsigned short* __restrict__ bmatT,
                                              const float* __restrict__ escale,
                                              float* __restrict__ He2) {
    __shared__ union {
        unsigned short AB[2][8192];   // [0]=As,[1]=Bs: [row(128)][k(64)] swizzled
        float red[128 * 20];          // epilogue reduce tile (overlays As)
    } sm;
    __shared__ float escT[1024];      // [t(8)][row(128)]

    const int b  = blockIdx.x & 7;    // XCD swizzle
    const int rt = (blockIdx.x >> 3) & 7;
    const int z  = blockIdx.x >> 6;   // 0..15
    const int og = z & 3;             // channel group (16 ch)
    const int kh = z >> 2;            // K quarter
    const int n0 = rt * 128;
    const int kb = kh * 256;

    const int tid  = threadIdx.x;
    const int wave = tid >> 6, lane = tid & 63;
    const int wr = wave >> 1, wc = wave & 1;

    {   // stage escale [8t][128 rows]
        const int t = tid >> 5, r4 = (tid & 31) * 4;
        *(float4*)&escT[t * 128 + r4] =
            *(const float4*)&escale[(size_t)(b * 8 + t) * 1024 + n0 + r4];
    }

    const unsigned short* gA = G + ((size_t)b << 20) + (size_t)n0 * 1024 + kb;
    const unsigned short* gB = bmatT + (size_t)(b * 512 + og * 16) * 1024 + kb;

    const int r8  = lane >> 3;        // 0..7: row within 8-row segment
    const int grp = lane & 7;         // dest 16B k-group (of 8)
    const int gsw = grp ^ r8;         // swizzled source k-group

    f32x4_t acc[4][4];
    #pragma unroll
    for (int i = 0; i < 4; ++i)
        #pragma unroll
        for (int j = 0; j < 4; ++j) acc[i][j] = f32x4_t{0.f, 0.f, 0.f, 0.f};

    const int fr = lane & 15, quad = lane >> 4;

    for (int kk = 0; kk < 4; ++kk) {
        const int k0 = kk * 64;
        __syncthreads();              // all waves done with prev As/Bs
        #pragma unroll
        for (int i = 0; i < 4; ++i) {
            const int seg = wave * 4 + i;              // 0..15, 8 rows each
            gld_lds16((char*)sm.AB[0] + seg * 1024 + lane * 16,
                      gA + (size_t)(seg * 8 + r8) * 1024 + k0 + gsw * 8);
            const int t8 = seg >> 1, oo0 = (seg & 1) * 8;
            gld_lds16((char*)sm.AB[1] + seg * 1024 + lane * 16,
                      gB + (size_t)(t8 * 64 + oo0 + r8) * 1024 + k0 + gsw * 8);
        }
        __syncthreads();              // DMA drained -> tiles visible
        #pragma unroll
        for (int s = 0; s < 2; ++s) {
            const int sw = ((s * 4 + quad) ^ (fr & 7)) * 16;
            uint4 afr[4], bfr[4];
            #pragma unroll
            for (int i = 0; i < 4; ++i)
                afr[i] = *(const uint4*)((const char*)sm.AB[0]
                         + (wr * 64 + i * 16 + fr) * 128 + sw);
            #pragma unroll
            for (int j = 0; j < 4; ++j)
                bfr[j] = *(const uint4*)((const char*)sm.AB[1]
                         + (wc * 64 + j * 16 + fr) * 128 + sw);
            #pragma unroll
            for (int i = 0; i < 4; ++i)
                #pragma unroll
                for (int j = 0; j < 4; ++j)
                    acc[i][j] = __builtin_amdgcn_mfma_f32_16x16x32_bf16(
                        __builtin_bit_cast(bf16x8_t, afr[i]),
                        __builtin_bit_cast(bf16x8_t, bfr[j]),
                        acc[i][j], 0, 0, 0);
        }
    }
    __syncthreads();                  // done reading AB before red overlay

    // epilogue: res[row][oo] = sum_j escale[wc*4+j][row] * acc[.][j][.]
    const int oo = lane & 15;
    float res[4][4];
    #pragma unroll
    for (int i = 0; i < 4; ++i)
        #pragma unroll
        for (int r = 0; r < 4; ++r) {
            const int lr = wr * 64 + i * 16 + quad * 4 + r;
            float s = 0.f;
            #pragma unroll
            for (int j = 0; j < 4; ++j)
                s += escT[(wc * 4 + j) * 128 + lr] * acc[i][j][r];
            res[i][r] = s;
        }
    if (wc == 0) {
        #pragma unroll
        for (int i = 0; i < 4; ++i)
            #pragma unroll
            for (int r = 0; r < 4; ++r) {
                const int lr = wr * 64 + i * 16 + quad * 4 + r;
                sm.red[lr * 20 + oo] = res[i][r];
            }
    }
    __syncthreads();
    if (wc == 1) {
        #pragma unroll
        for (int i = 0; i < 4; ++i)
            #pragma unroll
            for (int r = 0; r < 4; ++r) {
                const int lr = wr * 64 + i * 16 + quad * 4 + r;
                sm.red[lr * 20 + oo] += res[i][r];
            }
    }
    __syncthreads();
    float* dst = He2 + (size_t)kh * 524288 + (size_t)(b * 1024 + n0) * 64 + og * 16;
    #pragma unroll
    for (int it = 0; it < 2; ++it) {
        const int L = it * 256 + tid;
        const int row = L >> 2, c4 = (L & 3) * 4;
        *(float4*)(dst + (size_t)row * 64 + c4) = *(const float4*)&sm.red[row * 20 + c4];
    }
}

// K4: out = sum of 4 He2 partials; BN stats via atomics + device ticket barrier;
// then normalize+ReLU from registers. 256 blocks (1/CU, all co-resident).
__global__ __launch_bounds__(256) void k_fin(const float* __restrict__ He2,
                                             float* __restrict__ out,
                                             float* __restrict__ bns,
                                             const float* __restrict__ gamma,
                                             const float* __restrict__ beta) {
    __shared__ float s1[16][64], s2[16][64];
    __shared__ float bnsl[128];
    const int tid = threadIdx.x;
    const float4* H4 = (const float4*)He2;
    unsigned int* cnt = (unsigned int*)(bns + 128);

    float4 v[2];
    float a0 = 0.f, a1 = 0.f, a2 = 0.f, a3 = 0.f;
    float q0 = 0.f, q1 = 0.f, q2 = 0.f, q3 = 0.f;
    #pragma unroll
    for (int it = 0; it < 2; ++it) {
        const size_t idx = (size_t)blockIdx.x * 512 + it * 256 + tid;
        float4 s = make_float4(0.f, 0.f, 0.f, 0.f);
        #pragma unroll
        for (int p = 0; p < 4; ++p) {
            float4 h = H4[(size_t)p * 131072 + idx];
            s.x += h.x; s.y += h.y; s.z += h.z; s.w += h.w;
        }
        v[it] = s;
        a0 += s.x; a1 += s.y; a2 += s.z; a3 += s.w;
        q0 += s.x * s.x; q1 += s.y * s.y; q2 += s.z * s.z; q3 += s.w * s.w;
    }
    const int g = tid >> 4, o4 = (tid & 15) * 4;
    *(float4*)&s1[g][o4] = make_float4(a0, a1, a2, a3);
    *(float4*)&s2[g][o4] = make_float4(q0, q1, q2, q3);
    __syncthreads();
    if (tid < 64) {
        float sa = 0.f, sb = 0.f;
        #pragma unroll
        for (int r = 0; r < 16; ++r) { sa += s1[r][tid]; sb += s2[r][tid]; }
        atomicAdd(&bns[tid], sa);
        atomicAdd(&bns[64 + tid], sb);
    }
    __threadfence();
    __syncthreads();
    if (tid == 0) {
        atomicAdd(cnt, 1u);
        while (__hip_atomic_load(cnt, __ATOMIC_ACQUIRE, __HIP_MEMORY_SCOPE_AGENT) < 256u)
            __builtin_amdgcn_s_sleep(8);
    }
    __syncthreads();
    if (tid < 128)
        bnsl[tid] = __hip_atomic_load(&bns[tid], __ATOMIC_RELAXED, __HIP_MEMORY_SCOPE_AGENT);
    __syncthreads();

    const float invn = 1.f / 8192.f;
    float mm[4], ww[4], bb[4];
    #pragma unroll
    for (int c = 0; c < 4; ++c) {
        const int ch = o4 + c;
        const float m = bnsl[ch] * invn;
        const float var = bnsl[64 + ch] * invn - m * m;
        mm[c] = m;
        ww[c] = __frsqrt_rn(var + BN_EPS) * gamma[ch];
        bb[c] = beta[ch];
    }
    #pragma unroll
    for (int it = 0; it < 2; ++it) {
        const size_t idx = (size_t)blockIdx.x * 512 + it * 256 + tid;
        float4 x = v[it];
        x.x = fmaxf((x.x - mm[0]) * ww[0] + bb[0], 0.f);
        x.y = fmaxf((x.y - mm[1]) * ww[1] + bb[1], 0.f);
        x.z = fmaxf((x.z - mm[2]) * ww[2] + bb[2], 0.f);
        x.w = fmaxf((x.w - mm[3]) * ww[3] + bb[3], 0.f);
        ((float4*)out)[idx] = x;
    }
}

extern "C" void kernel_launch(void* const* d_in, const int* in_sizes, int n_in,
                              void* d_out, int out_size, void* d_ws, size_t ws_size,
                              hipStream_t stream) {
    const float* points = (const float*)d_in[0];
    const float* trans  = (const float*)d_in[1];
    const float* funcs  = (const float*)d_in[2];
    const float* ktens  = (const float*)d_in[3];
    const float* gamma  = (const float*)d_in[4];
    const float* beta   = (const float*)d_in[5];
    float* out = (float*)d_out;

    float* ws      = (float*)d_ws;
    float* escale  = ws;                    // 65536 f
    float* bns     = escale + 65536;        // 136 f (incl. counter)
    float* rowsum  = bns + 136;             // 8192 f
    float* He2     = rowsum + 8192;         // 2097152 f
    unsigned short* kpb   = (unsigned short*)(He2 + 2097152);   // 32768 us
    unsigned short* G     = kpb + 32768;                        // 8388608 us
    unsigned short* bmatT = G + 8388608;                        // 4194304 us

    k_g<<<1152, 256, 0, stream>>>(points, ktens, G, rowsum, kpb, bns);
    k_prep<<<256, 256, 0, stream>>>(points, trans, funcs, kpb, rowsum, bmatT, escale);
    k_gemm<<<1024, 256, 0, stream>>>(G, bmatT, escale, He2);
    k_fin<<<256, 256, 0, stream>>>(He2, out, bns, gamma, beta);
}

// Round 9
// 141.098 us; speedup vs baseline: 1.0317x; 1.0317x over previous
//
#include <hip/hip_runtime.h>
#include <hip/hip_bf16.h>
#include <cstdint>
#include <cstddef>

#define BN_EPS 1e-5f

typedef float f32x4_t __attribute__((ext_vector_type(4)));
typedef __bf16 bf16x8_t __attribute__((ext_vector_type(8)));

__device__ __forceinline__ unsigned short f2bf(float f) {
    __hip_bfloat16 h = __float2bfloat16(f);
    return __builtin_bit_cast(unsigned short, h);
}

// async global->LDS, 16B/lane; LDS dest is wave-uniform base + lane*16.
__device__ __forceinline__ void gld_lds16(void* lds, const void* gp) {
#if __has_builtin(__builtin_amdgcn_global_load_lds)
    __builtin_amdgcn_global_load_lds(
        (const __attribute__((address_space(1))) unsigned int*)gp,
        (__attribute__((address_space(3))) unsigned int*)lds, 16, 0, 0);
#else
    *(uint4*)lds = *(const uint4*)gp;
#endif
}

// ---------------- ws layout ----------------
// kpb    : bf16  [512 col=t*64+o][64 c]   32768 us
// escale : float [B][T][N]                65536 f
// bns    : float sum[64]+sumsq[64]+cnt    136 f (cnt @ [128] as uint)
// rowsum : float [B][N]                   8192 f
// He2    : float [4 part][B*N][64]        2097152 f  (8 MB)
// G      : bf16  [B][N][N]                8388608 us (16 MB)
// bmatT  : bf16  [B][512 col][N(m)]       4194304 us (8 MB)

// K1: blocks 0..1023: G[b][row][*] bf16 + rowsum (column octet in registers).
//     blocks 1024..1151: repack k_tensor -> kpb bf16 [t*64+o][c]; zero bns+cnt.
__global__ __launch_bounds__(256) void k_g(const float* __restrict__ points,
                                           const float* __restrict__ ktens,
                                           unsigned short* __restrict__ G,
                                           float* __restrict__ rowsum,
                                           unsigned short* __restrict__ kpb,
                                           float* __restrict__ bns) {
    __shared__ float praw[3072];
    __shared__ float px[1024], py[1024], pz[1024], hq[1024];
    __shared__ float rs[8];

    const int tid = threadIdx.x;
    if (blockIdx.x >= 1024) {             // pack branch (block-uniform)
        const int i = (blockIdx.x - 1024) * 256 + tid;   // i = (t*64+o)*64 + c
        const int t = i >> 12, o = (i >> 6) & 63, c = i & 63;
        kpb[i] = f2bf(ktens[(o * 64 + c) * 8 + t]);
        if (blockIdx.x == 1024 && tid < 136) bns[tid] = 0.f;   // stats + counter
        return;
    }

    const int b  = blockIdx.x & 7;               // XCD swizzle
    const int n0 = (blockIdx.x >> 3) * 8;

    for (int i = tid; i < 3072; i += 256) praw[i] = points[b * 3072 + i];
    if (tid < 8) rs[tid] = 0.f;
    __syncthreads();
    for (int n = tid; n < 1024; n += 256) {
        float x = praw[n * 3], y = praw[n * 3 + 1], z = praw[n * 3 + 2];
        px[n] = x; py[n] = y; pz[n] = z;
        hq[n] = -0.5f * (x * x + y * y + z * z);
    }
    __syncthreads();

    const int rhalf = tid >> 7;                  // 0/1: which row of the pair
    const int c0 = (tid & 127) * 8;              // column octet
    float vx[8], vy[8], vz[8], vh[8];
    *(float4*)&vx[0] = *(const float4*)&px[c0];
    *(float4*)&vx[4] = *(const float4*)&px[c0 + 4];
    *(float4*)&vy[0] = *(const float4*)&py[c0];
    *(float4*)&vy[4] = *(const float4*)&py[c0 + 4];
    *(float4*)&vz[0] = *(const float4*)&pz[c0];
    *(float4*)&vz[4] = *(const float4*)&pz[c0 + 4];
    *(float4*)&vh[0] = *(const float4*)&hq[c0];
    *(float4*)&vh[4] = *(const float4*)&hq[c0 + 4];

    unsigned short* gb = G + ((size_t)b << 20);

    #pragma unroll
    for (int u = 0; u < 4; ++u) {
        const int rl = u * 2 + rhalf;
        const int row = n0 + rl;
        const float rx = px[row], ry = py[row], rz = pz[row], hr = hq[row];
        unsigned short us[8];
        float ssum = 0.f;
        #pragma unroll
        for (int j = 0; j < 8; ++j) {
            float e = __expf(hr + vh[j] + rx * vx[j] + ry * vy[j] + rz * vz[j]);
            ssum += e;
            us[j] = f2bf(e);
        }
        uint4 pk;
        pk.x = us[0] | ((unsigned int)us[1] << 16);
        pk.y = us[2] | ((unsigned int)us[3] << 16);
        pk.z = us[4] | ((unsigned int)us[5] << 16);
        pk.w = us[6] | ((unsigned int)us[7] << 16);
        *(uint4*)(gb + (size_t)row * 1024 + c0) = pk;
        #pragma unroll
        for (int m = 32; m; m >>= 1) ssum += __shfl_xor(ssum, m, 64);
        if ((tid & 63) == 0) atomicAdd(&rs[rl], ssum);
    }
    __syncthreads();
    if (tid < 8) rowsum[b * 1024 + n0 + tid] = rs[tid];
}

// K2: MFMA prep GEMM: bmat[m][col] = (sfac[t,m]/rowsum[m]) * sum_c funcs[m,c]*kpb[col,c]
// grid 256 = b(8) x mt(8,128 rows) x ct(4,128 cols); 4 waves; K=64; also escale.
__global__ __launch_bounds__(256) void k_prep(const float* __restrict__ points,
                                              const float* __restrict__ trans,
                                              const float* __restrict__ funcs,
                                              const unsigned short* __restrict__ kpb,
                                              const float* __restrict__ rowsum,
                                              unsigned short* __restrict__ bmatT,
                                              float* __restrict__ escale) {
    __shared__ unsigned short Asm[128 * 72];   // [m][c] bf16, stride 72
    __shared__ unsigned short Bsm[128 * 72];   // [col][c] bf16, stride 72
    __shared__ float sfacl[256];               // [tloc(2)][m(128)]

    const int b  = blockIdx.x & 7;
    const int mt = (blockIdx.x >> 3) & 7;
    const int ct = blockIdx.x >> 6;            // 0..3 (t-pair)
    const int m0 = mt * 128;

    const int tid  = threadIdx.x;
    const int wave = tid >> 6, lane = tid & 63;
    const int wr = wave >> 1, wc = wave & 1;
    const int fr = lane & 15, quad = lane >> 4;

    // sfac + escale (global reads only; no LDS dependency)
    {
        const int tloc = tid >> 7, m = tid & 127;
        const int t = ct * 2 + tloc;
        const float tx = trans[b * 24 + t * 3], ty = trans[b * 24 + t * 3 + 1],
                    tz = trans[b * 24 + t * 3 + 2];
        const float* pp = &points[(size_t)(b * 1024 + m0 + m) * 3];
        const float ptd = pp[0] * tx + pp[1] * ty + pp[2] * tz;
        const float tsq = tx * tx + ty * ty + tz * tz;
        const float rsv = rowsum[b * 1024 + m0 + m];
        sfacl[tloc * 128 + m] = __expf(-ptd - 0.5f * tsq) / rsv;
        escale[(size_t)(b * 8 + t) * 1024 + m0 + m] = __expf(ptd);
    }
    // stage A: funcs fp32 -> bf16 LDS [m][c]
    #pragma unroll
    for (int rep = 0; rep < 2; ++rep) {
        const int m = rep * 64 + (tid >> 2);
        const int c16 = (tid & 3) * 16;
        const float* fp = &funcs[((size_t)(b * 1024) + m0 + m) * 64 + c16];
        float4 f0 = *(const float4*)fp, f1 = *(const float4*)(fp + 4);
        float4 f2 = *(const float4*)(fp + 8), f3 = *(const float4*)(fp + 12);
        uint4 p0, p1;
        p0.x = f2bf(f0.x) | ((unsigned)f2bf(f0.y) << 16);
        p0.y = f2bf(f0.z) | ((unsigned)f2bf(f0.w) << 16);
        p0.z = f2bf(f1.x) | ((unsigned)f2bf(f1.y) << 16);
        p0.w = f2bf(f1.z) | ((unsigned)f2bf(f1.w) << 16);
        p1.x = f2bf(f2.x) | ((unsigned)f2bf(f2.y) << 16);
        p1.y = f2bf(f2.z) | ((unsigned)f2bf(f2.w) << 16);
        p1.z = f2bf(f3.x) | ((unsigned)f2bf(f3.y) << 16);
        p1.w = f2bf(f3.z) | ((unsigned)f2bf(f3.w) << 16);
        *(uint4*)&Asm[m * 72 + c16] = p0;
        *(uint4*)&Asm[m * 72 + c16 + 8] = p1;
    }
    // stage B: kpb bf16 -> LDS [col][c]
    #pragma unroll
    for (int rep = 0; rep < 4; ++rep) {
        const int col = rep * 32 + (tid >> 3);
        const int c8 = (tid & 7) * 8;
        uint4 v = *(const uint4*)&kpb[(size_t)(ct * 128 + col) * 64 + c8];
        *(uint4*)&Bsm[col * 72 + c8] = v;
    }
    __syncthreads();

    f32x4_t acc[4][4];
    #pragma unroll
    for (int i = 0; i < 4; ++i)
        #pragma unroll
        for (int j = 0; j < 4; ++j) acc[i][j] = f32x4_t{0.f, 0.f, 0.f, 0.f};

    #pragma unroll
    for (int s = 0; s < 2; ++s) {
        uint4 afr[4], bfr[4];
        #pragma unroll
        for (int i = 0; i < 4; ++i)
            afr[i] = *(const uint4*)&Asm[(wr * 64 + i * 16 + fr) * 72 + s * 32 + quad * 8];
        #pragma unroll
        for (int j = 0; j < 4; ++j)
            bfr[j] = *(const uint4*)&Bsm[(wc * 64 + j * 16 + fr) * 72 + s * 32 + quad * 8];
        #pragma unroll
        for (int i = 0; i < 4; ++i)
            #pragma unroll
            for (int j = 0; j < 4; ++j)
                acc[i][j] = __builtin_amdgcn_mfma_f32_16x16x32_bf16(
                    __builtin_bit_cast(bf16x8_t, afr[i]),
                    __builtin_bit_cast(bf16x8_t, bfr[j]),
                    acc[i][j], 0, 0, 0);
    }

    // epilogue: scale and pack 4 consecutive m per lane -> bmatT[b][col][m]
    #pragma unroll
    for (int i = 0; i < 4; ++i) {
        #pragma unroll
        for (int j = 0; j < 4; ++j) {
            const int colg = ct * 128 + wc * 64 + j * 16 + fr;
            ushort4 pk;
            {
                const int mb = wr * 64 + i * 16 + quad * 4;
                pk.x = f2bf(acc[i][j][0] * sfacl[wc * 128 + mb + 0]);
                pk.y = f2bf(acc[i][j][1] * sfacl[wc * 128 + mb + 1]);
                pk.z = f2bf(acc[i][j][2] * sfacl[wc * 128 + mb + 2]);
                pk.w = f2bf(acc[i][j][3] * sfacl[wc * 128 + mb + 3]);
                *(ushort4*)&bmatT[(size_t)(b * 512 + colg) * 1024 + m0 + mb] = pk;
            }
        }
    }
}

// K3: bf16 GEMM, BK=32 (R6-proven config), global_load_lds + XOR-4 k-group swizzle.
// grid 1024 = b(8) x rt(8) x [og(4) x kh(4)]; 4 waves; 128x128 tile, K/4=256.
// NOTE: BK=64 variants (R7/R8) regressed ~20 µs: VGPR crosses the 128 cliff
// (16->8 waves/CU) or spills under a forced launch bound. Keep BK=32.
__global__ __launch_bounds__(256) void k_gemm(const unsigned short* __restrict__ G,
                                              const unsigned short* __restrict__ bmatT,
                                              const float* __restrict__ escale,
                                              float* __restrict__ He2) {
    __shared__ unsigned short As[4096];   // [row(128)][k(32)] bf16, k-swizzled
    __shared__ unsigned short Bs[4096];   // [c'(128)=t*16+oo][k(32)] bf16, k-swizzled
    __shared__ float escT[1024];          // [t(8)][row(128)]
    __shared__ float red[128 * 20];       // padded reduce tile [row][16ch]

    const int b  = blockIdx.x & 7;        // XCD swizzle
    const int rt = (blockIdx.x >> 3) & 7;
    const int z  = blockIdx.x >> 6;       // 0..15
    const int og = z & 3;                 // channel group (16 ch)
    const int kh = z >> 2;                // K quarter
    const int n0 = rt * 128;
    const int kb = kh * 256;

    const int tid  = threadIdx.x;
    const int wave = tid >> 6, lane = tid & 63;
    const int wr = wave >> 1, wc = wave & 1;

    {   // stage escale [8t][128 rows]
        const int t = tid >> 5, r4 = (tid & 31) * 4;
        *(float4*)&escT[t * 128 + r4] =
            *(const float4*)&escale[(size_t)(b * 8 + t) * 1024 + n0 + r4];
    }

    const unsigned short* gA = G + ((size_t)b << 20) + (size_t)n0 * 1024 + kb;
    const unsigned short* gB = bmatT + (size_t)(b * 512 + og * 16) * 1024 + kb;

    const int r16 = lane >> 2;            // row within 16-seg
    const int kq  = lane & 3;             // dest 16B k-group
    const int gsw = kq ^ (r16 & 3);       // swizzled source k-group
    const size_t gAoff = (size_t)r16 * 1024 + gsw * 8;

    f32x4_t acc[4][4];
    #pragma unroll
    for (int i = 0; i < 4; ++i)
        #pragma unroll
        for (int j = 0; j < 4; ++j) acc[i][j] = f32x4_t{0.f, 0.f, 0.f, 0.f};

    const int fr = lane & 15;             // fragment row/col part
    const int swoff = ((lane >> 4) ^ (fr & 3)) << 4;   // swizzled frag byte offset

    for (int kk = 0; kk < 8; ++kk) {
        const int k0 = kk * 32;
        __syncthreads();                  // all waves done with prev As/Bs
        #pragma unroll
        for (int i = 0; i < 2; ++i) {
            const int seg = wave * 2 + i;   // 16 rows (A) / one t: 16 cols (B)
            gld_lds16((char*)As + seg * 1024 + lane * 16,
                      gA + (size_t)(seg * 16) * 1024 + k0 + gAoff);
            gld_lds16((char*)Bs + seg * 1024 + lane * 16,
                      gB + (size_t)(seg * 64) * 1024 + (size_t)r16 * 1024 + k0 + gsw * 8);
        }
        __syncthreads();                  // DMA drained -> tiles visible
        uint4 afr[4], bfr[4];
        #pragma unroll
        for (int i = 0; i < 4; ++i)
            afr[i] = *(const uint4*)((const char*)As + (wr * 64 + i * 16 + fr) * 64 + swoff);
        #pragma unroll
        for (int j = 0; j < 4; ++j)
            bfr[j] = *(const uint4*)((const char*)Bs + (wc * 64 + j * 16 + fr) * 64 + swoff);
        #pragma unroll
        for (int i = 0; i < 4; ++i)
            #pragma unroll
            for (int j = 0; j < 4; ++j)
                acc[i][j] = __builtin_amdgcn_mfma_f32_16x16x32_bf16(
                    __builtin_bit_cast(bf16x8_t, afr[i]),
                    __builtin_bit_cast(bf16x8_t, bfr[j]),
                    acc[i][j], 0, 0, 0);
    }

    // epilogue: res[row][oo] = sum_j escale[wc*4+j][row] * acc[.][j][.]
    const int quad = lane >> 4, oo = lane & 15;
    float res[4][4];
    #pragma unroll
    for (int i = 0; i < 4; ++i)
        #pragma unroll
        for (int r = 0; r < 4; ++r) {
            const int lr = wr * 64 + i * 16 + quad * 4 + r;
            float s = 0.f;
            #pragma unroll
            for (int j = 0; j < 4; ++j)
                s += escT[(wc * 4 + j) * 128 + lr] * acc[i][j][r];
            res[i][r] = s;
        }
    if (wc == 0) {
        #pragma unroll
        for (int i = 0; i < 4; ++i)
            #pragma unroll
            for (int r = 0; r < 4; ++r) {
                const int lr = wr * 64 + i * 16 + quad * 4 + r;
                red[lr * 20 + oo] = res[i][r];
            }
    }
    __syncthreads();
    if (wc == 1) {
        #pragma unroll
        for (int i = 0; i < 4; ++i)
            #pragma unroll
            for (int r = 0; r < 4; ++r) {
                const int lr = wr * 64 + i * 16 + quad * 4 + r;
                red[lr * 20 + oo] += res[i][r];
            }
    }
    __syncthreads();
    float* dst = He2 + (size_t)kh * 524288 + (size_t)(b * 1024 + n0) * 64 + og * 16;
    #pragma unroll
    for (int it = 0; it < 2; ++it) {
        const int L = it * 256 + tid;
        const int row = L >> 2, c4 = (L & 3) * 4;
        *(float4*)(dst + (size_t)row * 64 + c4) = *(const float4*)&red[row * 20 + c4];
    }
}

// K4: out = sum of 4 He2 partials; BN stats via atomics + device ticket barrier;
// then normalize+ReLU from registers. 256 blocks (1/CU, all co-resident).
__global__ __launch_bounds__(256) void k_fin(const float* __restrict__ He2,
                                             float* __restrict__ out,
                                             float* __restrict__ bns,
                                             const float* __restrict__ gamma,
                                             const float* __restrict__ beta) {
    __shared__ float s1[16][64], s2[16][64];
    __shared__ float bnsl[128];
    const int tid = threadIdx.x;
    const float4* H4 = (const float4*)He2;
    unsigned int* cnt = (unsigned int*)(bns + 128);

    float4 v[2];
    float a0 = 0.f, a1 = 0.f, a2 = 0.f, a3 = 0.f;
    float q0 = 0.f, q1 = 0.f, q2 = 0.f, q3 = 0.f;
    #pragma unroll
    for (int it = 0; it < 2; ++it) {
        const size_t idx = (size_t)blockIdx.x * 512 + it * 256 + tid;
        float4 s = make_float4(0.f, 0.f, 0.f, 0.f);
        #pragma unroll
        for (int p = 0; p < 4; ++p) {
            float4 h = H4[(size_t)p * 131072 + idx];
            s.x += h.x; s.y += h.y; s.z += h.z; s.w += h.w;
        }
        v[it] = s;
        a0 += s.x; a1 += s.y; a2 += s.z; a3 += s.w;
        q0 += s.x * s.x; q1 += s.y * s.y; q2 += s.z * s.z; q3 += s.w * s.w;
    }
    const int g = tid >> 4, o4 = (tid & 15) * 4;
    *(float4*)&s1[g][o4] = make_float4(a0, a1, a2, a3);
    *(float4*)&s2[g][o4] = make_float4(q0, q1, q2, q3);
    __syncthreads();
    if (tid < 64) {
        float sa = 0.f, sb = 0.f;
        #pragma unroll
        for (int r = 0; r < 16; ++r) { sa += s1[r][tid]; sb += s2[r][tid]; }
        atomicAdd(&bns[tid], sa);
        atomicAdd(&bns[64 + tid], sb);
    }
    __threadfence();
    __syncthreads();
    if (tid == 0) {
        atomicAdd(cnt, 1u);
        while (__hip_atomic_load(cnt, __ATOMIC_ACQUIRE, __HIP_MEMORY_SCOPE_AGENT) < 256u)
            __builtin_amdgcn_s_sleep(8);
    }
    __syncthreads();
    if (tid < 128)
        bnsl[tid] = __hip_atomic_load(&bns[tid], __ATOMIC_RELAXED, __HIP_MEMORY_SCOPE_AGENT);
    __syncthreads();

    const float invn = 1.f / 8192.f;
    float mm[4], ww[4], bb[4];
    #pragma unroll
    for (int c = 0; c < 4; ++c) {
        const int ch = o4 + c;
        const float m = bnsl[ch] * invn;
        const float var = bnsl[64 + ch] * invn - m * m;
        mm[c] = m;
        ww[c] = __frsqrt_rn(var + BN_EPS) * gamma[ch];
        bb[c] = beta[ch];
    }
    #pragma unroll
    for (int it = 0; it < 2; ++it) {
        const size_t idx = (size_t)blockIdx.x * 512 + it * 256 + tid;
        float4 x = v[it];
        x.x = fmaxf((x.x - mm[0]) * ww[0] + bb[0], 0.f);
        x.y = fmaxf((x.y - mm[1]) * ww[1] + bb[1], 0.f);
        x.z = fmaxf((x.z - mm[2]) * ww[2] + bb[2], 0.f);
        x.w = fmaxf((x.w - mm[3]) * ww[3] + bb[3], 0.f);
        ((float4*)out)[idx] = x;
    }
}

extern "C" void kernel_launch(void* const* d_in, const int* in_sizes, int n_in,
                              void* d_out, int out_size, void* d_ws, size_t ws_size,
                              hipStream_t stream) {
    const float* points = (const float*)d_in[0];
    const float* trans  = (const float*)d_in[1];
    const float* funcs  = (const float*)d_in[2];
    const float* ktens  = (const float*)d_in[3];
    const float* gamma  = (const float*)d_in[4];
    const float* beta   = (const float*)d_in[5];
    float* out = (float*)d_out;

    float* ws      = (float*)d_ws;
    float* escale  = ws;                    // 65536 f
    float* bns     = escale + 65536;        // 136 f (incl. counter)
    float* rowsum  = bns + 136;             // 8192 f
    float* He2     = rowsum + 8192;         // 2097152 f
    unsigned short* kpb   = (unsigned short*)(He2 + 2097152);   // 32768 us
    unsigned short* G     = kpb + 32768;                        // 8388608 us
    unsigned short* bmatT = G + 8388608;                        // 4194304 us

    k_g<<<1152, 256, 0, stream>>>(points, ktens, G, rowsum, kpb, bns);
    k_prep<<<256, 256, 0, stream>>>(points, trans, funcs, kpb, rowsum, bmatT, escale);
    k_gemm<<<1024, 256, 0, stream>>>(G, bmatT, escale, He2);
    k_fin<<<256, 256, 0, stream>>>(He2, out, bns, gamma, beta);
}

// Round 10
// 117.354 us; speedup vs baseline: 1.2404x; 1.2023x over previous
//
#include <hip/hip_runtime.h>
#include <hip/hip_bf16.h>
#include <cstdint>
#include <cstddef>

#define BN_EPS 1e-5f

typedef float f32x4_t __attribute__((ext_vector_type(4)));
typedef __bf16 bf16x8_t __attribute__((ext_vector_type(8)));

__device__ __forceinline__ unsigned short f2bf(float f) {
    __hip_bfloat16 h = __float2bfloat16(f);
    return __builtin_bit_cast(unsigned short, h);
}

// async global->LDS, 16B/lane; LDS dest is wave-uniform base + lane*16.
__device__ __forceinline__ void gld_lds16(void* lds, const void* gp) {
#if __has_builtin(__builtin_amdgcn_global_load_lds)
    __builtin_amdgcn_global_load_lds(
        (const __attribute__((address_space(1))) unsigned int*)gp,
        (__attribute__((address_space(3))) unsigned int*)lds, 16, 0, 0);
#else
    *(uint4*)lds = *(const uint4*)gp;
#endif
}

// ---------------- ws layout ----------------
// kpb    : bf16  [512 col=t*64+o][64 c]   32768 us
// escale : float [B][T][N]                65536 f
// bns    : float sum[64]+sumsq[64]        128 f
// rowsum : float [B][N]                   8192 f
// He2    : float [4 part][B*N][64]        2097152 f  (8 MB)
// G      : bf16  [B][N][N]                8388608 us (16 MB)
// bmatT  : bf16  [B][512 col][N(m)]       4194304 us (8 MB)
//
// NOTE (R7-R9 lesson): fusing the BN tail behind a device-scope ticket barrier
// (fence-agent + acquire spin) cost ~20 µs on multi-XCD gfx950 — far more than
// the launch it saved. Kernel-boundary sync is ~free; keep k_fin/k_bn split.

// K1: blocks 0..1023: G[b][row][*] bf16 + rowsum (column octet in registers).
//     blocks 1024..1151: repack k_tensor -> kpb bf16 [t*64+o][c]; zero bns.
__global__ __launch_bounds__(256) void k_g(const float* __restrict__ points,
                                           const float* __restrict__ ktens,
                                           unsigned short* __restrict__ G,
                                           float* __restrict__ rowsum,
                                           unsigned short* __restrict__ kpb,
                                           float* __restrict__ bns) {
    __shared__ float praw[3072];
    __shared__ float px[1024], py[1024], pz[1024], hq[1024];
    __shared__ float rs[8];

    const int tid = threadIdx.x;
    if (blockIdx.x >= 1024) {             // pack branch (block-uniform)
        const int i = (blockIdx.x - 1024) * 256 + tid;   // i = (t*64+o)*64 + c
        const int t = i >> 12, o = (i >> 6) & 63, c = i & 63;
        kpb[i] = f2bf(ktens[(o * 64 + c) * 8 + t]);
        if (blockIdx.x == 1024 && tid < 128) bns[tid] = 0.f;
        return;
    }

    const int b  = blockIdx.x & 7;               // XCD swizzle
    const int n0 = (blockIdx.x >> 3) * 8;

    for (int i = tid; i < 3072; i += 256) praw[i] = points[b * 3072 + i];
    if (tid < 8) rs[tid] = 0.f;
    __syncthreads();
    for (int n = tid; n < 1024; n += 256) {
        float x = praw[n * 3], y = praw[n * 3 + 1], z = praw[n * 3 + 2];
        px[n] = x; py[n] = y; pz[n] = z;
        hq[n] = -0.5f * (x * x + y * y + z * z);
    }
    __syncthreads();

    const int rhalf = tid >> 7;                  // 0/1: which row of the pair
    const int c0 = (tid & 127) * 8;              // column octet
    float vx[8], vy[8], vz[8], vh[8];
    *(float4*)&vx[0] = *(const float4*)&px[c0];
    *(float4*)&vx[4] = *(const float4*)&px[c0 + 4];
    *(float4*)&vy[0] = *(const float4*)&py[c0];
    *(float4*)&vy[4] = *(const float4*)&py[c0 + 4];
    *(float4*)&vz[0] = *(const float4*)&pz[c0];
    *(float4*)&vz[4] = *(const float4*)&pz[c0 + 4];
    *(float4*)&vh[0] = *(const float4*)&hq[c0];
    *(float4*)&vh[4] = *(const float4*)&hq[c0 + 4];

    unsigned short* gb = G + ((size_t)b << 20);

    #pragma unroll
    for (int u = 0; u < 4; ++u) {
        const int rl = u * 2 + rhalf;
        const int row = n0 + rl;
        const float rx = px[row], ry = py[row], rz = pz[row], hr = hq[row];
        unsigned short us[8];
        float ssum = 0.f;
        #pragma unroll
        for (int j = 0; j < 8; ++j) {
            float e = __expf(hr + vh[j] + rx * vx[j] + ry * vy[j] + rz * vz[j]);
            ssum += e;
            us[j] = f2bf(e);
        }
        uint4 pk;
        pk.x = us[0] | ((unsigned int)us[1] << 16);
        pk.y = us[2] | ((unsigned int)us[3] << 16);
        pk.z = us[4] | ((unsigned int)us[5] << 16);
        pk.w = us[6] | ((unsigned int)us[7] << 16);
        *(uint4*)(gb + (size_t)row * 1024 + c0) = pk;
        #pragma unroll
        for (int m = 32; m; m >>= 1) ssum += __shfl_xor(ssum, m, 64);
        if ((tid & 63) == 0) atomicAdd(&rs[rl], ssum);
    }
    __syncthreads();
    if (tid < 8) rowsum[b * 1024 + n0 + tid] = rs[tid];
}

// K2: MFMA prep GEMM: bmat[m][col] = (sfac[t,m]/rowsum[m]) * sum_c funcs[m,c]*kpb[col,c]
// grid 256 = b(8) x mt(8,128 rows) x ct(4,128 cols); 4 waves; K=64; also escale.
__global__ __launch_bounds__(256) void k_prep(const float* __restrict__ points,
                                              const float* __restrict__ trans,
                                              const float* __restrict__ funcs,
                                              const unsigned short* __restrict__ kpb,
                                              const float* __restrict__ rowsum,
                                              unsigned short* __restrict__ bmatT,
                                              float* __restrict__ escale) {
    __shared__ unsigned short Asm[128 * 72];   // [m][c] bf16, stride 72
    __shared__ unsigned short Bsm[128 * 72];   // [col][c] bf16, stride 72
    __shared__ float sfacl[256];               // [tloc(2)][m(128)]

    const int b  = blockIdx.x & 7;
    const int mt = (blockIdx.x >> 3) & 7;
    const int ct = blockIdx.x >> 6;            // 0..3 (t-pair)
    const int m0 = mt * 128;

    const int tid  = threadIdx.x;
    const int wave = tid >> 6, lane = tid & 63;
    const int wr = wave >> 1, wc = wave & 1;
    const int fr = lane & 15, quad = lane >> 4;

    // sfac + escale (global reads only; no LDS dependency)
    {
        const int tloc = tid >> 7, m = tid & 127;
        const int t = ct * 2 + tloc;
        const float tx = trans[b * 24 + t * 3], ty = trans[b * 24 + t * 3 + 1],
                    tz = trans[b * 24 + t * 3 + 2];
        const float* pp = &points[(size_t)(b * 1024 + m0 + m) * 3];
        const float ptd = pp[0] * tx + pp[1] * ty + pp[2] * tz;
        const float tsq = tx * tx + ty * ty + tz * tz;
        const float rsv = rowsum[b * 1024 + m0 + m];
        sfacl[tloc * 128 + m] = __expf(-ptd - 0.5f * tsq) / rsv;
        escale[(size_t)(b * 8 + t) * 1024 + m0 + m] = __expf(ptd);
    }
    // stage A: funcs fp32 -> bf16 LDS [m][c]
    #pragma unroll
    for (int rep = 0; rep < 2; ++rep) {
        const int m = rep * 64 + (tid >> 2);
        const int c16 = (tid & 3) * 16;
        const float* fp = &funcs[((size_t)(b * 1024) + m0 + m) * 64 + c16];
        float4 f0 = *(const float4*)fp, f1 = *(const float4*)(fp + 4);
        float4 f2 = *(const float4*)(fp + 8), f3 = *(const float4*)(fp + 12);
        uint4 p0, p1;
        p0.x = f2bf(f0.x) | ((unsigned)f2bf(f0.y) << 16);
        p0.y = f2bf(f0.z) | ((unsigned)f2bf(f0.w) << 16);
        p0.z = f2bf(f1.x) | ((unsigned)f2bf(f1.y) << 16);
        p0.w = f2bf(f1.z) | ((unsigned)f2bf(f1.w) << 16);
        p1.x = f2bf(f2.x) | ((unsigned)f2bf(f2.y) << 16);
        p1.y = f2bf(f2.z) | ((unsigned)f2bf(f2.w) << 16);
        p1.z = f2bf(f3.x) | ((unsigned)f2bf(f3.y) << 16);
        p1.w = f2bf(f3.z) | ((unsigned)f2bf(f3.w) << 16);
        *(uint4*)&Asm[m * 72 + c16] = p0;
        *(uint4*)&Asm[m * 72 + c16 + 8] = p1;
    }
    // stage B: kpb bf16 -> LDS [col][c]
    #pragma unroll
    for (int rep = 0; rep < 4; ++rep) {
        const int col = rep * 32 + (tid >> 3);
        const int c8 = (tid & 7) * 8;
        uint4 v = *(const uint4*)&kpb[(size_t)(ct * 128 + col) * 64 + c8];
        *(uint4*)&Bsm[col * 72 + c8] = v;
    }
    __syncthreads();

    f32x4_t acc[4][4];
    #pragma unroll
    for (int i = 0; i < 4; ++i)
        #pragma unroll
        for (int j = 0; j < 4; ++j) acc[i][j] = f32x4_t{0.f, 0.f, 0.f, 0.f};

    #pragma unroll
    for (int s = 0; s < 2; ++s) {
        uint4 afr[4], bfr[4];
        #pragma unroll
        for (int i = 0; i < 4; ++i)
            afr[i] = *(const uint4*)&Asm[(wr * 64 + i * 16 + fr) * 72 + s * 32 + quad * 8];
        #pragma unroll
        for (int j = 0; j < 4; ++j)
            bfr[j] = *(const uint4*)&Bsm[(wc * 64 + j * 16 + fr) * 72 + s * 32 + quad * 8];
        #pragma unroll
        for (int i = 0; i < 4; ++i)
            #pragma unroll
            for (int j = 0; j < 4; ++j)
                acc[i][j] = __builtin_amdgcn_mfma_f32_16x16x32_bf16(
                    __builtin_bit_cast(bf16x8_t, afr[i]),
                    __builtin_bit_cast(bf16x8_t, bfr[j]),
                    acc[i][j], 0, 0, 0);
    }

    // epilogue: scale and pack 4 consecutive m per lane -> bmatT[b][col][m]
    #pragma unroll
    for (int i = 0; i < 4; ++i) {
        #pragma unroll
        for (int j = 0; j < 4; ++j) {
            const int colg = ct * 128 + wc * 64 + j * 16 + fr;
            ushort4 pk;
            {
                const int mb = wr * 64 + i * 16 + quad * 4;
                pk.x = f2bf(acc[i][j][0] * sfacl[wc * 128 + mb + 0]);
                pk.y = f2bf(acc[i][j][1] * sfacl[wc * 128 + mb + 1]);
                pk.z = f2bf(acc[i][j][2] * sfacl[wc * 128 + mb + 2]);
                pk.w = f2bf(acc[i][j][3] * sfacl[wc * 128 + mb + 3]);
                *(ushort4*)&bmatT[(size_t)(b * 512 + colg) * 1024 + m0 + mb] = pk;
            }
        }
    }
}

// K3: bf16 GEMM, BK=32, global_load_lds + XOR-4 k-group swizzle.
// grid 1024 = b(8) x rt(8) x [og(4) x kh(4)]; 4 waves; 128x128 tile, K/4=256.
__global__ __launch_bounds__(256) void k_gemm(const unsigned short* __restrict__ G,
                                              const unsigned short* __restrict__ bmatT,
                                              const float* __restrict__ escale,
                                              float* __restrict__ He2) {
    __shared__ unsigned short As[4096];   // [row(128)][k(32)] bf16, k-swizzled
    __shared__ unsigned short Bs[4096];   // [c'(128)=t*16+oo][k(32)] bf16, k-swizzled
    __shared__ float escT[1024];          // [t(8)][row(128)]
    __shared__ float red[128 * 20];       // padded reduce tile [row][16ch]

    const int b  = blockIdx.x & 7;        // XCD swizzle
    const int rt = (blockIdx.x >> 3) & 7;
    const int z  = blockIdx.x >> 6;       // 0..15
    const int og = z & 3;                 // channel group (16 ch)
    const int kh = z >> 2;                // K quarter
    const int n0 = rt * 128;
    const int kb = kh * 256;

    const int tid  = threadIdx.x;
    const int wave = tid >> 6, lane = tid & 63;
    const int wr = wave >> 1, wc = wave & 1;

    {   // stage escale [8t][128 rows]
        const int t = tid >> 5, r4 = (tid & 31) * 4;
        *(float4*)&escT[t * 128 + r4] =
            *(const float4*)&escale[(size_t)(b * 8 + t) * 1024 + n0 + r4];
    }

    const unsigned short* gA = G + ((size_t)b << 20) + (size_t)n0 * 1024 + kb;
    const unsigned short* gB = bmatT + (size_t)(b * 512 + og * 16) * 1024 + kb;

    const int r16 = lane >> 2;            // row within 16-seg
    const int kq  = lane & 3;             // dest 16B k-group
    const int gsw = kq ^ (r16 & 3);       // swizzled source k-group
    const size_t gAoff = (size_t)r16 * 1024 + gsw * 8;

    f32x4_t acc[4][4];
    #pragma unroll
    for (int i = 0; i < 4; ++i)
        #pragma unroll
        for (int j = 0; j < 4; ++j) acc[i][j] = f32x4_t{0.f, 0.f, 0.f, 0.f};

    const int fr = lane & 15;             // fragment row/col part
    const int swoff = ((lane >> 4) ^ (fr & 3)) << 4;   // swizzled frag byte offset

    for (int kk = 0; kk < 8; ++kk) {
        const int k0 = kk * 32;
        __syncthreads();                  // all waves done with prev As/Bs
        #pragma unroll
        for (int i = 0; i < 2; ++i) {
            const int seg = wave * 2 + i;   // 16 rows (A) / one t: 16 cols (B)
            gld_lds16((char*)As + seg * 1024 + lane * 16,
                      gA + (size_t)(seg * 16) * 1024 + k0 + gAoff);
            gld_lds16((char*)Bs + seg * 1024 + lane * 16,
                      gB + (size_t)(seg * 64) * 1024 + (size_t)r16 * 1024 + k0 + gsw * 8);
        }
        __syncthreads();                  // DMA drained -> tiles visible
        uint4 afr[4], bfr[4];
        #pragma unroll
        for (int i = 0; i < 4; ++i)
            afr[i] = *(const uint4*)((const char*)As + (wr * 64 + i * 16 + fr) * 64 + swoff);
        #pragma unroll
        for (int j = 0; j < 4; ++j)
            bfr[j] = *(const uint4*)((const char*)Bs + (wc * 64 + j * 16 + fr) * 64 + swoff);
        #pragma unroll
        for (int i = 0; i < 4; ++i)
            #pragma unroll
            for (int j = 0; j < 4; ++j)
                acc[i][j] = __builtin_amdgcn_mfma_f32_16x16x32_bf16(
                    __builtin_bit_cast(bf16x8_t, afr[i]),
                    __builtin_bit_cast(bf16x8_t, bfr[j]),
                    acc[i][j], 0, 0, 0);
    }

    // epilogue: res[row][oo] = sum_j escale[wc*4+j][row] * acc[.][j][.]
    const int quad = lane >> 4, oo = lane & 15;
    float res[4][4];
    #pragma unroll
    for (int i = 0; i < 4; ++i)
        #pragma unroll
        for (int r = 0; r < 4; ++r) {
            const int lr = wr * 64 + i * 16 + quad * 4 + r;
            float s = 0.f;
            #pragma unroll
            for (int j = 0; j < 4; ++j)
                s += escT[(wc * 4 + j) * 128 + lr] * acc[i][j][r];
            res[i][r] = s;
        }
    if (wc == 0) {
        #pragma unroll
        for (int i = 0; i < 4; ++i)
            #pragma unroll
            for (int r = 0; r < 4; ++r) {
                const int lr = wr * 64 + i * 16 + quad * 4 + r;
                red[lr * 20 + oo] = res[i][r];
            }
    }
    __syncthreads();
    if (wc == 1) {
        #pragma unroll
        for (int i = 0; i < 4; ++i)
            #pragma unroll
            for (int r = 0; r < 4; ++r) {
                const int lr = wr * 64 + i * 16 + quad * 4 + r;
                red[lr * 20 + oo] += res[i][r];
            }
    }
    __syncthreads();
    float* dst = He2 + (size_t)kh * 524288 + (size_t)(b * 1024 + n0) * 64 + og * 16;
    #pragma unroll
    for (int it = 0; it < 2; ++it) {
        const int L = it * 256 + tid;
        const int row = L >> 2, c4 = (L & 3) * 4;
        *(float4*)(dst + (size_t)row * 64 + c4) = *(const float4*)&red[row * 20 + c4];
    }
}

// K4: out = sum of 4 He2 partials; fused BN sum/sumsq
__global__ __launch_bounds__(256) void k_fin(const float* __restrict__ He2,
                                             float* __restrict__ out,
                                             float* __restrict__ bns) {
    __shared__ float s1[16][64], s2[16][64];
    const int tid = threadIdx.x;
    const float4* H4 = (const float4*)He2;
    float a0 = 0.f, a1 = 0.f, a2 = 0.f, a3 = 0.f;
    float q0 = 0.f, q1 = 0.f, q2 = 0.f, q3 = 0.f;
    #pragma unroll
    for (int it = 0; it < 2; ++it) {
        const size_t idx = (size_t)blockIdx.x * 512 + it * 256 + tid;
        float4 s = make_float4(0.f, 0.f, 0.f, 0.f);
        #pragma unroll
        for (int p = 0; p < 4; ++p) {
            float4 h = H4[(size_t)p * 131072 + idx];
            s.x += h.x; s.y += h.y; s.z += h.z; s.w += h.w;
        }
        ((float4*)out)[idx] = s;
        a0 += s.x; a1 += s.y; a2 += s.z; a3 += s.w;
        q0 += s.x * s.x; q1 += s.y * s.y; q2 += s.z * s.z; q3 += s.w * s.w;
    }
    const int g = tid >> 4, o4 = (tid & 15) * 4;
    *(float4*)&s1[g][o4] = make_float4(a0, a1, a2, a3);
    *(float4*)&s2[g][o4] = make_float4(q0, q1, q2, q3);
    __syncthreads();
    if (tid < 64) {
        float sa = 0.f, sb = 0.f;
        #pragma unroll
        for (int r = 0; r < 16; ++r) { sa += s1[r][tid]; sb += s2[r][tid]; }
        atomicAdd(&bns[tid], sa);
        atomicAdd(&bns[64 + tid], sb);
    }
}

// K5: in-place BN (training stats) + ReLU
__global__ __launch_bounds__(256) void k_bn(float* __restrict__ out,
                                            const float* __restrict__ bns,
                                            const float* __restrict__ gamma,
                                            const float* __restrict__ beta) {
    const int i = blockIdx.x * 256 + threadIdx.x;
    const int o4 = (i & 15) * 4;
    float4 x = ((float4*)out)[i];
    const float4 s  = *(const float4*)&bns[o4];
    const float4 s2 = *(const float4*)&bns[64 + o4];
    const float4 gm = *(const float4*)&gamma[o4];
    const float4 bt = *(const float4*)&beta[o4];
    const float invn = 1.f / 8192.f;
    float m, v, w;
    m = s.x * invn; v = s2.x * invn - m * m; w = __frsqrt_rn(v + BN_EPS) * gm.x;
    x.x = fmaxf((x.x - m) * w + bt.x, 0.f);
    m = s.y * invn; v = s2.y * invn - m * m; w = __frsqrt_rn(v + BN_EPS) * gm.y;
    x.y = fmaxf((x.y - m) * w + bt.y, 0.f);
    m = s.z * invn; v = s2.z * invn - m * m; w = __frsqrt_rn(v + BN_EPS) * gm.z;
    x.z = fmaxf((x.z - m) * w + bt.z, 0.f);
    m = s.w * invn; v = s2.w * invn - m * m; w = __frsqrt_rn(v + BN_EPS) * gm.w;
    x.w = fmaxf((x.w - m) * w + bt.w, 0.f);
    ((float4*)out)[i] = x;
}

extern "C" void kernel_launch(void* const* d_in, const int* in_sizes, int n_in,
                              void* d_out, int out_size, void* d_ws, size_t ws_size,
                              hipStream_t stream) {
    const float* points = (const float*)d_in[0];
    const float* trans  = (const float*)d_in[1];
    const float* funcs  = (const float*)d_in[2];
    const float* ktens  = (const float*)d_in[3];
    const float* gamma  = (const float*)d_in[4];
    const float* beta   = (const float*)d_in[5];
    float* out = (float*)d_out;

    float* ws      = (float*)d_ws;
    float* escale  = ws;                    // 65536 f
    float* bns     = escale + 65536;        // 128 f
    float* rowsum  = bns + 128;             // 8192 f
    float* He2     = rowsum + 8192;         // 2097152 f
    unsigned short* kpb   = (unsigned short*)(He2 + 2097152);   // 32768 us
    unsigned short* G     = kpb + 32768;                        // 8388608 us
    unsigned short* bmatT = G + 8388608;                        // 4194304 us

    k_g<<<1152, 256, 0, stream>>>(points, ktens, G, rowsum, kpb, bns);
    k_prep<<<256, 256, 0, stream>>>(points, trans, funcs, kpb, rowsum, bmatT, escale);
    k_gemm<<<1024, 256, 0, stream>>>(G, bmatT, escale, He2);
    k_fin<<<256, 256, 0, stream>>>(He2, out, bns);
    k_bn<<<512, 256, 0, stream>>>(out, bns, gamma, beta);
}

// Round 11
// 114.546 us; speedup vs baseline: 1.2708x; 1.0245x over previous
//
#include <hip/hip_runtime.h>
#include <hip/hip_bf16.h>
#include <cstdint>
#include <cstddef>

#define BN_EPS 1e-5f

typedef float f32x4_t __attribute__((ext_vector_type(4)));
typedef __bf16 bf16x8_t __attribute__((ext_vector_type(8)));

__device__ __forceinline__ unsigned short f2bf(float f) {
    __hip_bfloat16 h = __float2bfloat16(f);
    return __builtin_bit_cast(unsigned short, h);
}

// async global->LDS, 16B/lane; LDS dest is wave-uniform base + lane*16.
__device__ __forceinline__ void gld_lds16(void* lds, const void* gp) {
#if __has_builtin(__builtin_amdgcn_global_load_lds)
    __builtin_amdgcn_global_load_lds(
        (const __attribute__((address_space(1))) unsigned int*)gp,
        (__attribute__((address_space(3))) unsigned int*)lds, 16, 0, 0);
#else
    *(uint4*)lds = *(const uint4*)gp;
#endif
}

// ---------------- ws layout ----------------
// kpb    : bf16  [512 col=t*64+o][64 c]   32768 us
// escale : float [B][T][N]                65536 f
// bns    : float sum[64]+sumsq[64]        128 f
// rowsum : float [B][N]                   8192 f
// He2    : float [4 part][B*N][64]        2097152 f  (8 MB)
// G      : bf16  [B][N][N]                8388608 us (16 MB)
// bmatT  : bf16  [B][512 col][N(m)]       4194304 us (8 MB)
//
// NOTE (R7-R9 lesson): fusing the BN tail behind a device-scope ticket barrier
// (fence-agent + acquire spin) cost ~20 µs on multi-XCD gfx950 — far more than
// the launch it saved. Kernel-boundary sync is ~free; keep k_fin/k_bn split.

// K1: blocks 0..1023: G[b][row][*] bf16 + rowsum (column octet in registers).
//     blocks 1024..1151: repack k_tensor -> kpb bf16 [t*64+o][c]; zero bns.
__global__ __launch_bounds__(256) void k_g(const float* __restrict__ points,
                                           const float* __restrict__ ktens,
                                           unsigned short* __restrict__ G,
                                           float* __restrict__ rowsum,
                                           unsigned short* __restrict__ kpb,
                                           float* __restrict__ bns) {
    __shared__ float praw[3072];
    __shared__ float px[1024], py[1024], pz[1024], hq[1024];
    __shared__ float part[8][128];   // rowsum partials [row][col-octet]
    __shared__ float p2[8][32];

    const int tid = threadIdx.x;
    if (blockIdx.x >= 1024) {             // pack branch (block-uniform)
        const int i = (blockIdx.x - 1024) * 256 + tid;   // i = (t*64+o)*64 + c
        const int t = i >> 12, o = (i >> 6) & 63, c = i & 63;
        kpb[i] = f2bf(ktens[(o * 64 + c) * 8 + t]);
        if (blockIdx.x == 1024 && tid < 128) bns[tid] = 0.f;
        return;
    }

    const int b  = blockIdx.x & 7;               // XCD swizzle
    const int n0 = (blockIdx.x >> 3) * 8;

    for (int i = tid; i < 3072; i += 256) praw[i] = points[b * 3072 + i];
    __syncthreads();
    for (int n = tid; n < 1024; n += 256) {
        float x = praw[n * 3], y = praw[n * 3 + 1], z = praw[n * 3 + 2];
        px[n] = x; py[n] = y; pz[n] = z;
        hq[n] = -0.5f * (x * x + y * y + z * z);
    }
    __syncthreads();

    const int rhalf = tid >> 7;                  // 0/1: which row of the pair
    const int c0 = (tid & 127) * 8;              // column octet
    float vx[8], vy[8], vz[8], vh[8];
    *(float4*)&vx[0] = *(const float4*)&px[c0];
    *(float4*)&vx[4] = *(const float4*)&px[c0 + 4];
    *(float4*)&vy[0] = *(const float4*)&py[c0];
    *(float4*)&vy[4] = *(const float4*)&py[c0 + 4];
    *(float4*)&vz[0] = *(const float4*)&pz[c0];
    *(float4*)&vz[4] = *(const float4*)&pz[c0 + 4];
    *(float4*)&vh[0] = *(const float4*)&hq[c0];
    *(float4*)&vh[4] = *(const float4*)&hq[c0 + 4];

    unsigned short* gb = G + ((size_t)b << 20);

    #pragma unroll
    for (int u = 0; u < 4; ++u) {
        const int rl = u * 2 + rhalf;
        const int row = n0 + rl;
        const float rx = px[row], ry = py[row], rz = pz[row], hr = hq[row];
        unsigned short us[8];
        float ssum = 0.f;
        #pragma unroll
        for (int j = 0; j < 8; ++j) {
            float e = __expf(hr + vh[j] + rx * vx[j] + ry * vy[j] + rz * vz[j]);
            ssum += e;
            us[j] = f2bf(e);
        }
        uint4 pk;
        pk.x = us[0] | ((unsigned int)us[1] << 16);
        pk.y = us[2] | ((unsigned int)us[3] << 16);
        pk.z = us[4] | ((unsigned int)us[5] << 16);
        pk.w = us[6] | ((unsigned int)us[7] << 16);
        *(uint4*)(gb + (size_t)row * 1024 + c0) = pk;
        part[rl][tid & 127] = ssum;              // 1 LDS write (no shfl butterfly)
    }
    __syncthreads();
    {   // level 1: 256 thr, float4 reduce 128 -> 32 partials per row
        const int row = tid >> 5, c4l = (tid & 31) * 4;
        float4 p = *(const float4*)&part[row][c4l];
        p2[row][tid & 31] = p.x + p.y + p.z + p.w;
    }
    __syncthreads();
    if (tid < 8) {   // level 2: 8 thr finish their row
        float s = 0.f;
        #pragma unroll
        for (int q = 0; q < 8; ++q) {
            float4 v = *(const float4*)&p2[tid][q * 4];
            s += v.x + v.y + v.z + v.w;
        }
        rowsum[b * 1024 + n0 + tid] = s;
    }
}

// K2: MFMA prep GEMM: bmat[m][col] = (sfac[t,m]/rowsum[m]) * sum_c funcs[m,c]*kpb[col,c]
// grid 256 = b(8) x mt(8,128 rows) x ct(4,128 cols); 4 waves; K=64; also escale.
__global__ __launch_bounds__(256) void k_prep(const float* __restrict__ points,
                                              const float* __restrict__ trans,
                                              const float* __restrict__ funcs,
                                              const unsigned short* __restrict__ kpb,
                                              const float* __restrict__ rowsum,
                                              unsigned short* __restrict__ bmatT,
                                              float* __restrict__ escale) {
    __shared__ unsigned short Asm[128 * 72];   // [m][c] bf16, stride 72
    __shared__ unsigned short Bsm[128 * 72];   // [col][c] bf16, stride 72
    __shared__ float sfacl[256];               // [tloc(2)][m(128)]

    const int b  = blockIdx.x & 7;
    const int mt = (blockIdx.x >> 3) & 7;
    const int ct = blockIdx.x >> 6;            // 0..3 (t-pair)
    const int m0 = mt * 128;

    const int tid  = threadIdx.x;
    const int wave = tid >> 6, lane = tid & 63;
    const int wr = wave >> 1, wc = wave & 1;
    const int fr = lane & 15, quad = lane >> 4;

    // sfac + escale (global reads only; no LDS dependency)
    {
        const int tloc = tid >> 7, m = tid & 127;
        const int t = ct * 2 + tloc;
        const float tx = trans[b * 24 + t * 3], ty = trans[b * 24 + t * 3 + 1],
                    tz = trans[b * 24 + t * 3 + 2];
        const float* pp = &points[(size_t)(b * 1024 + m0 + m) * 3];
        const float ptd = pp[0] * tx + pp[1] * ty + pp[2] * tz;
        const float tsq = tx * tx + ty * ty + tz * tz;
        const float rsv = rowsum[b * 1024 + m0 + m];
        sfacl[tloc * 128 + m] = __expf(-ptd - 0.5f * tsq) / rsv;
        escale[(size_t)(b * 8 + t) * 1024 + m0 + m] = __expf(ptd);
    }
    // stage A: funcs fp32 -> bf16 LDS [m][c]
    #pragma unroll
    for (int rep = 0; rep < 2; ++rep) {
        const int m = rep * 64 + (tid >> 2);
        const int c16 = (tid & 3) * 16;
        const float* fp = &funcs[((size_t)(b * 1024) + m0 + m) * 64 + c16];
        float4 f0 = *(const float4*)fp, f1 = *(const float4*)(fp + 4);
        float4 f2 = *(const float4*)(fp + 8), f3 = *(const float4*)(fp + 12);
        uint4 p0, p1;
        p0.x = f2bf(f0.x) | ((unsigned)f2bf(f0.y) << 16);
        p0.y = f2bf(f0.z) | ((unsigned)f2bf(f0.w) << 16);
        p0.z = f2bf(f1.x) | ((unsigned)f2bf(f1.y) << 16);
        p0.w = f2bf(f1.z) | ((unsigned)f2bf(f1.w) << 16);
        p1.x = f2bf(f2.x) | ((unsigned)f2bf(f2.y) << 16);
        p1.y = f2bf(f2.z) | ((unsigned)f2bf(f2.w) << 16);
        p1.z = f2bf(f3.x) | ((unsigned)f2bf(f3.y) << 16);
        p1.w = f2bf(f3.z) | ((unsigned)f2bf(f3.w) << 16);
        *(uint4*)&Asm[m * 72 + c16] = p0;
        *(uint4*)&Asm[m * 72 + c16 + 8] = p1;
    }
    // stage B: kpb bf16 -> LDS [col][c]
    #pragma unroll
    for (int rep = 0; rep < 4; ++rep) {
        const int col = rep * 32 + (tid >> 3);
        const int c8 = (tid & 7) * 8;
        uint4 v = *(const uint4*)&kpb[(size_t)(ct * 128 + col) * 64 + c8];
        *(uint4*)&Bsm[col * 72 + c8] = v;
    }
    __syncthreads();

    f32x4_t acc[4][4];
    #pragma unroll
    for (int i = 0; i < 4; ++i)
        #pragma unroll
        for (int j = 0; j < 4; ++j) acc[i][j] = f32x4_t{0.f, 0.f, 0.f, 0.f};

    #pragma unroll
    for (int s = 0; s < 2; ++s) {
        uint4 afr[4], bfr[4];
        #pragma unroll
        for (int i = 0; i < 4; ++i)
            afr[i] = *(const uint4*)&Asm[(wr * 64 + i * 16 + fr) * 72 + s * 32 + quad * 8];
        #pragma unroll
        for (int j = 0; j < 4; ++j)
            bfr[j] = *(const uint4*)&Bsm[(wc * 64 + j * 16 + fr) * 72 + s * 32 + quad * 8];
        #pragma unroll
        for (int i = 0; i < 4; ++i)
            #pragma unroll
            for (int j = 0; j < 4; ++j)
                acc[i][j] = __builtin_amdgcn_mfma_f32_16x16x32_bf16(
                    __builtin_bit_cast(bf16x8_t, afr[i]),
                    __builtin_bit_cast(bf16x8_t, bfr[j]),
                    acc[i][j], 0, 0, 0);
    }

    // epilogue: scale and pack 4 consecutive m per lane -> bmatT[b][col][m]
    #pragma unroll
    for (int i = 0; i < 4; ++i) {
        #pragma unroll
        for (int j = 0; j < 4; ++j) {
            const int colg = ct * 128 + wc * 64 + j * 16 + fr;
            ushort4 pk;
            {
                const int mb = wr * 64 + i * 16 + quad * 4;
                pk.x = f2bf(acc[i][j][0] * sfacl[wc * 128 + mb + 0]);
                pk.y = f2bf(acc[i][j][1] * sfacl[wc * 128 + mb + 1]);
                pk.z = f2bf(acc[i][j][2] * sfacl[wc * 128 + mb + 2]);
                pk.w = f2bf(acc[i][j][3] * sfacl[wc * 128 + mb + 3]);
                *(ushort4*)&bmatT[(size_t)(b * 512 + colg) * 1024 + m0 + mb] = pk;
            }
        }
    }
}

// K3: bf16 GEMM, BK=32, global_load_lds + XOR-4 k-group swizzle.
// grid 1024 = b(8) x rt(8) x [og(4) x kh(4)]; 4 waves; 128x128 tile, K/4=256.
// Each wave owns 32 rows x ALL 128 cols (2 A-frags x 8 B-frags): the t-reduction
// completes in registers -> no cross-wave red tile, no epilogue barriers.
__global__ __launch_bounds__(256) void k_gemm(const unsigned short* __restrict__ G,
                                              const unsigned short* __restrict__ bmatT,
                                              const float* __restrict__ escale,
                                              float* __restrict__ He2) {
    __shared__ unsigned short As[4096];   // [row(128)][k(32)] bf16, k-swizzled
    __shared__ unsigned short Bs[4096];   // [c'(128)=t*16+oo][k(32)] bf16, k-swizzled
    __shared__ float escT[1024];          // [t(8)][row(128)]

    const int b  = blockIdx.x & 7;        // XCD swizzle
    const int rt = (blockIdx.x >> 3) & 7;
    const int z  = blockIdx.x >> 6;       // 0..15
    const int og = z & 3;                 // channel group (16 ch)
    const int kh = z >> 2;                // K quarter
    const int n0 = rt * 128;
    const int kb = kh * 256;

    const int tid  = threadIdx.x;
    const int wave = tid >> 6, lane = tid & 63;

    {   // stage escale [8t][128 rows]
        const int t = tid >> 5, r4 = (tid & 31) * 4;
        *(float4*)&escT[t * 128 + r4] =
            *(const float4*)&escale[(size_t)(b * 8 + t) * 1024 + n0 + r4];
    }

    const unsigned short* gA = G + ((size_t)b << 20) + (size_t)n0 * 1024 + kb;
    const unsigned short* gB = bmatT + (size_t)(b * 512 + og * 16) * 1024 + kb;

    const int r16 = lane >> 2;            // row within 16-seg
    const int kq  = lane & 3;             // dest 16B k-group
    const int gsw = kq ^ (r16 & 3);       // swizzled source k-group
    const size_t gAoff = (size_t)r16 * 1024 + gsw * 8;

    f32x4_t acc[2][8];
    #pragma unroll
    for (int i = 0; i < 2; ++i)
        #pragma unroll
        for (int j = 0; j < 8; ++j) acc[i][j] = f32x4_t{0.f, 0.f, 0.f, 0.f};

    const int fr = lane & 15;             // fragment row/col part
    const int swoff = ((lane >> 4) ^ (fr & 3)) << 4;   // swizzled frag byte offset
    const int row_base = wave * 32;       // this wave's 32 output rows

    for (int kk = 0; kk < 8; ++kk) {
        const int k0 = kk * 32;
        __syncthreads();                  // all waves done with prev As/Bs
        #pragma unroll
        for (int i = 0; i < 2; ++i) {
            const int seg = wave * 2 + i;   // 16 rows (A) / one t: 16 cols (B)
            gld_lds16((char*)As + seg * 1024 + lane * 16,
                      gA + (size_t)(seg * 16) * 1024 + k0 + gAoff);
            gld_lds16((char*)Bs + seg * 1024 + lane * 16,
                      gB + (size_t)(seg * 64) * 1024 + (size_t)r16 * 1024 + k0 + gsw * 8);
        }
        __syncthreads();                  // DMA drained -> tiles visible
        uint4 afr0 = *(const uint4*)((const char*)As + (row_base + fr) * 64 + swoff);
        uint4 afr1 = *(const uint4*)((const char*)As + (row_base + 16 + fr) * 64 + swoff);
        #pragma unroll
        for (int j = 0; j < 8; ++j) {     // one B-frag live at a time (VGPR frugal)
            uint4 bfr = *(const uint4*)((const char*)Bs + (j * 16 + fr) * 64 + swoff);
            acc[0][j] = __builtin_amdgcn_mfma_f32_16x16x32_bf16(
                __builtin_bit_cast(bf16x8_t, afr0),
                __builtin_bit_cast(bf16x8_t, bfr), acc[0][j], 0, 0, 0);
            acc[1][j] = __builtin_amdgcn_mfma_f32_16x16x32_bf16(
                __builtin_bit_cast(bf16x8_t, afr1),
                __builtin_bit_cast(bf16x8_t, bfr), acc[1][j], 0, 0, 0);
        }
    }

    // epilogue: res[row][oo] = sum_t escT[t][row] * acc  — all in registers
    const int quad = lane >> 4, oo = lane & 15;
    float* dst = He2 + (size_t)kh * 524288 + (size_t)(b * 1024 + n0) * 64 + og * 16;
    #pragma unroll
    for (int i = 0; i < 2; ++i) {
        #pragma unroll
        for (int r = 0; r < 4; ++r) {
            const int row = row_base + i * 16 + quad * 4 + r;
            float s = 0.f;
            #pragma unroll
            for (int j = 0; j < 8; ++j)
                s += escT[j * 128 + row] * acc[i][j][r];
            dst[(size_t)row * 64 + oo] = s;
        }
    }
}

// K4: out = sum of 4 He2 partials; fused BN sum/sumsq
__global__ __launch_bounds__(256) void k_fin(const float* __restrict__ He2,
                                             float* __restrict__ out,
                                             float* __restrict__ bns) {
    __shared__ float s1[16][64], s2[16][64];
    const int tid = threadIdx.x;
    const float4* H4 = (const float4*)He2;
    float a0 = 0.f, a1 = 0.f, a2 = 0.f, a3 = 0.f;
    float q0 = 0.f, q1 = 0.f, q2 = 0.f, q3 = 0.f;
    #pragma unroll
    for (int it = 0; it < 2; ++it) {
        const size_t idx = (size_t)blockIdx.x * 512 + it * 256 + tid;
        float4 s = make_float4(0.f, 0.f, 0.f, 0.f);
        #pragma unroll
        for (int p = 0; p < 4; ++p) {
            float4 h = H4[(size_t)p * 131072 + idx];
            s.x += h.x; s.y += h.y; s.z += h.z; s.w += h.w;
        }
        ((float4*)out)[idx] = s;
        a0 += s.x; a1 += s.y; a2 += s.z; a3 += s.w;
        q0 += s.x * s.x; q1 += s.y * s.y; q2 += s.z * s.z; q3 += s.w * s.w;
    }
    const int g = tid >> 4, o4 = (tid & 15) * 4;
    *(float4*)&s1[g][o4] = make_float4(a0, a1, a2, a3);
    *(float4*)&s2[g][o4] = make_float4(q0, q1, q2, q3);
    __syncthreads();
    if (tid < 64) {
        float sa = 0.f, sb = 0.f;
        #pragma unroll
        for (int r = 0; r < 16; ++r) { sa += s1[r][tid]; sb += s2[r][tid]; }
        atomicAdd(&bns[tid], sa);
        atomicAdd(&bns[64 + tid], sb);
    }
}

// K5: in-place BN (training stats) + ReLU
__global__ __launch_bounds__(256) void k_bn(float* __restrict__ out,
                                            const float* __restrict__ bns,
                                            const float* __restrict__ gamma,
                                            const float* __restrict__ beta) {
    const int i = blockIdx.x * 256 + threadIdx.x;
    const int o4 = (i & 15) * 4;
    float4 x = ((float4*)out)[i];
    const float4 s  = *(const float4*)&bns[o4];
    const float4 s2 = *(const float4*)&bns[64 + o4];
    const float4 gm = *(const float4*)&gamma[o4];
    const float4 bt = *(const float4*)&beta[o4];
    const float invn = 1.f / 8192.f;
    float m, v, w;
    m = s.x * invn; v = s2.x * invn - m * m; w = __frsqrt_rn(v + BN_EPS) * gm.x;
    x.x = fmaxf((x.x - m) * w + bt.x, 0.f);
    m = s.y * invn; v = s2.y * invn - m * m; w = __frsqrt_rn(v + BN_EPS) * gm.y;
    x.y = fmaxf((x.y - m) * w + bt.y, 0.f);
    m = s.z * invn; v = s2.z * invn - m * m; w = __frsqrt_rn(v + BN_EPS) * gm.z;
    x.z = fmaxf((x.z - m) * w + bt.z, 0.f);
    m = s.w * invn; v = s2.w * invn - m * m; w = __frsqrt_rn(v + BN_EPS) * gm.w;
    x.w = fmaxf((x.w - m) * w + bt.w, 0.f);
    ((float4*)out)[i] = x;
}

extern "C" void kernel_launch(void* const* d_in, const int* in_sizes, int n_in,
                              void* d_out, int out_size, void* d_ws, size_t ws_size,
                              hipStream_t stream) {
    const float* points = (const float*)d_in[0];
    const float* trans  = (const float*)d_in[1];
    const float* funcs  = (const float*)d_in[2];
    const float* ktens  = (const float*)d_in[3];
    const float* gamma  = (const float*)d_in[4];
    const float* beta   = (const float*)d_in[5];
    float* out = (float*)d_out;

    float* ws      = (float*)d_ws;
    float* escale  = ws;                    // 65536 f
    float* bns     = escale + 65536;        // 128 f
    float* rowsum  = bns + 128;             // 8192 f
    float* He2     = rowsum + 8192;         // 2097152 f
    unsigned short* kpb   = (unsigned short*)(He2 + 2097152);   // 32768 us
    unsigned short* G     = kpb + 32768;                        // 8388608 us
    unsigned short* bmatT = G + 8388608;                        // 4194304 us

    k_g<<<1152, 256, 0, stream>>>(points, ktens, G, rowsum, kpb, bns);
    k_prep<<<256, 256, 0, stream>>>(points, trans, funcs, kpb, rowsum, bmatT, escale);
    k_gemm<<<1024, 256, 0, stream>>>(G, bmatT, escale, He2);
    k_fin<<<256, 256, 0, stream>>>(He2, out, bns);
    k_bn<<<512, 256, 0, stream>>>(out, bns, gamma, beta);
}

// Round 12
// 113.698 us; speedup vs baseline: 1.2803x; 1.0075x over previous
//
#include <hip/hip_runtime.h>
#include <hip/hip_bf16.h>
#include <cstdint>
#include <cstddef>

#define BN_EPS 1e-5f

typedef float f32x4_t __attribute__((ext_vector_type(4)));
typedef __bf16 bf16x8_t __attribute__((ext_vector_type(8)));

__device__ __forceinline__ unsigned short f2bf(float f) {
    __hip_bfloat16 h = __float2bfloat16(f);
    return __builtin_bit_cast(unsigned short, h);
}
__device__ __forceinline__ float bf2f(unsigned short u) {
    unsigned int v = ((unsigned int)u) << 16;
    return __builtin_bit_cast(float, v);
}

// async global->LDS, 16B/lane; LDS dest is wave-uniform base + lane*16.
__device__ __forceinline__ void gld_lds16(void* lds, const void* gp) {
#if __has_builtin(__builtin_amdgcn_global_load_lds)
    __builtin_amdgcn_global_load_lds(
        (const __attribute__((address_space(1))) unsigned int*)gp,
        (__attribute__((address_space(3))) unsigned int*)lds, 16, 0, 0);
#else
    *(uint4*)lds = *(const uint4*)gp;
#endif
}

// ---------------- ws layout ----------------
// escale : float [B][T][N]                65536 f
// bns    : float sum[64]+sumsq[64]        128 f
// rowsum : float [B][N]                   8192 f
// He2    : bf16  [4 part][B*N][64]        2097152 us (4 MB)
// kpb    : bf16  [512 col=t*64+o][64 c]   32768 us
// G      : bf16  [B][N][N]                8388608 us (16 MB)
// bmatT  : bf16  [B][512 col][N(m)]       4194304 us (8 MB)
//
// NOTE (R7-R9 lesson): fusing the BN tail behind a device-scope ticket barrier
// (fence-agent + acquire spin) cost ~20 µs on multi-XCD gfx950 — far more than
// the launch it saved. Kernel-boundary sync is ~free; keep k_fin/k_bn split.
// NOTE (R7/R8 lesson): BK=64 crosses the 128-VGPR occupancy cliff (or spills
// under a forced launch bound). Keep BK=32, no min-waves bound.

// K1: blocks 0..1023: G[b][row][*] bf16 + rowsum (column octet in registers).
//     blocks 1024..1151: repack k_tensor -> kpb bf16 [t*64+o][c]; zero bns.
__global__ __launch_bounds__(256) void k_g(const float* __restrict__ points,
                                           const float* __restrict__ ktens,
                                           unsigned short* __restrict__ G,
                                           float* __restrict__ rowsum,
                                           unsigned short* __restrict__ kpb,
                                           float* __restrict__ bns) {
    __shared__ float praw[3072];
    __shared__ float px[1024], py[1024], pz[1024], hq[1024];
    __shared__ float part[8][128];   // rowsum partials [row][col-octet]
    __shared__ float p2[8][32];

    const int tid = threadIdx.x;
    if (blockIdx.x >= 1024) {             // pack branch (block-uniform)
        const int i = (blockIdx.x - 1024) * 256 + tid;   // i = (t*64+o)*64 + c
        const int t = i >> 12, o = (i >> 6) & 63, c = i & 63;
        kpb[i] = f2bf(ktens[(o * 64 + c) * 8 + t]);
        if (blockIdx.x == 1024 && tid < 128) bns[tid] = 0.f;
        return;
    }

    const int b  = blockIdx.x & 7;               // XCD swizzle
    const int n0 = (blockIdx.x >> 3) * 8;

    for (int i = tid; i < 3072; i += 256) praw[i] = points[b * 3072 + i];
    __syncthreads();
    for (int n = tid; n < 1024; n += 256) {
        float x = praw[n * 3], y = praw[n * 3 + 1], z = praw[n * 3 + 2];
        px[n] = x; py[n] = y; pz[n] = z;
        hq[n] = -0.5f * (x * x + y * y + z * z);
    }
    __syncthreads();

    const int rhalf = tid >> 7;                  // 0/1: which row of the pair
    const int c0 = (tid & 127) * 8;              // column octet
    float vx[8], vy[8], vz[8], vh[8];
    *(float4*)&vx[0] = *(const float4*)&px[c0];
    *(float4*)&vx[4] = *(const float4*)&px[c0 + 4];
    *(float4*)&vy[0] = *(const float4*)&py[c0];
    *(float4*)&vy[4] = *(const float4*)&py[c0 + 4];
    *(float4*)&vz[0] = *(const float4*)&pz[c0];
    *(float4*)&vz[4] = *(const float4*)&pz[c0 + 4];
    *(float4*)&vh[0] = *(const float4*)&hq[c0];
    *(float4*)&vh[4] = *(const float4*)&hq[c0 + 4];

    unsigned short* gb = G + ((size_t)b << 20);

    #pragma unroll
    for (int u = 0; u < 4; ++u) {
        const int rl = u * 2 + rhalf;
        const int row = n0 + rl;
        const float rx = px[row], ry = py[row], rz = pz[row], hr = hq[row];
        unsigned short us[8];
        float ssum = 0.f;
        #pragma unroll
        for (int j = 0; j < 8; ++j) {
            float e = __expf(hr + vh[j] + rx * vx[j] + ry * vy[j] + rz * vz[j]);
            ssum += e;
            us[j] = f2bf(e);
        }
        uint4 pk;
        pk.x = us[0] | ((unsigned int)us[1] << 16);
        pk.y = us[2] | ((unsigned int)us[3] << 16);
        pk.z = us[4] | ((unsigned int)us[5] << 16);
        pk.w = us[6] | ((unsigned int)us[7] << 16);
        *(uint4*)(gb + (size_t)row * 1024 + c0) = pk;
        part[rl][tid & 127] = ssum;              // 1 LDS write (no shfl butterfly)
    }
    __syncthreads();
    {   // level 1: 256 thr, float4 reduce 128 -> 32 partials per row
        const int row = tid >> 5, c4l = (tid & 31) * 4;
        float4 p = *(const float4*)&part[row][c4l];
        p2[row][tid & 31] = p.x + p.y + p.z + p.w;
    }
    __syncthreads();
    if (tid < 8) {   // level 2: 8 thr finish their row
        float s = 0.f;
        #pragma unroll
        for (int q = 0; q < 8; ++q) {
            float4 v = *(const float4*)&p2[tid][q * 4];
            s += v.x + v.y + v.z + v.w;
        }
        rowsum[b * 1024 + n0 + tid] = s;
    }
}

// K2: MFMA prep GEMM: bmat[m][col] = (sfac[t,m]/rowsum[m]) * sum_c funcs[m,c]*kpb[col,c]
// grid 256 = b(8) x mt(8,128 rows) x ct(4,128 cols); 4 waves; K=64; also escale.
__global__ __launch_bounds__(256) void k_prep(const float* __restrict__ points,
                                              const float* __restrict__ trans,
                                              const float* __restrict__ funcs,
                                              const unsigned short* __restrict__ kpb,
                                              const float* __restrict__ rowsum,
                                              unsigned short* __restrict__ bmatT,
                                              float* __restrict__ escale) {
    __shared__ unsigned short Asm[128 * 72];   // [m][c] bf16, stride 72
    __shared__ unsigned short Bsm[128 * 72];   // [col][c] bf16, stride 72
    __shared__ float sfacl[256];               // [tloc(2)][m(128)]

    const int b  = blockIdx.x & 7;
    const int mt = (blockIdx.x >> 3) & 7;
    const int ct = blockIdx.x >> 6;            // 0..3 (t-pair)
    const int m0 = mt * 128;

    const int tid  = threadIdx.x;
    const int wave = tid >> 6, lane = tid & 63;
    const int wr = wave >> 1, wc = wave & 1;
    const int fr = lane & 15, quad = lane >> 4;

    // sfac + escale (global reads only; no LDS dependency)
    {
        const int tloc = tid >> 7, m = tid & 127;
        const int t = ct * 2 + tloc;
        const float tx = trans[b * 24 + t * 3], ty = trans[b * 24 + t * 3 + 1],
                    tz = trans[b * 24 + t * 3 + 2];
        const float* pp = &points[(size_t)(b * 1024 + m0 + m) * 3];
        const float ptd = pp[0] * tx + pp[1] * ty + pp[2] * tz;
        const float tsq = tx * tx + ty * ty + tz * tz;
        const float rsv = rowsum[b * 1024 + m0 + m];
        sfacl[tloc * 128 + m] = __expf(-ptd - 0.5f * tsq) / rsv;
        escale[(size_t)(b * 8 + t) * 1024 + m0 + m] = __expf(ptd);
    }
    // stage A: funcs fp32 -> bf16 LDS [m][c]
    #pragma unroll
    for (int rep = 0; rep < 2; ++rep) {
        const int m = rep * 64 + (tid >> 2);
        const int c16 = (tid & 3) * 16;
        const float* fp = &funcs[((size_t)(b * 1024) + m0 + m) * 64 + c16];
        float4 f0 = *(const float4*)fp, f1 = *(const float4*)(fp + 4);
        float4 f2 = *(const float4*)(fp + 8), f3 = *(const float4*)(fp + 12);
        uint4 p0, p1;
        p0.x = f2bf(f0.x) | ((unsigned)f2bf(f0.y) << 16);
        p0.y = f2bf(f0.z) | ((unsigned)f2bf(f0.w) << 16);
        p0.z = f2bf(f1.x) | ((unsigned)f2bf(f1.y) << 16);
        p0.w = f2bf(f1.z) | ((unsigned)f2bf(f1.w) << 16);
        p1.x = f2bf(f2.x) | ((unsigned)f2bf(f2.y) << 16);
        p1.y = f2bf(f2.z) | ((unsigned)f2bf(f2.w) << 16);
        p1.z = f2bf(f3.x) | ((unsigned)f2bf(f3.y) << 16);
        p1.w = f2bf(f3.z) | ((unsigned)f2bf(f3.w) << 16);
        *(uint4*)&Asm[m * 72 + c16] = p0;
        *(uint4*)&Asm[m * 72 + c16 + 8] = p1;
    }
    // stage B: kpb bf16 -> LDS [col][c]
    #pragma unroll
    for (int rep = 0; rep < 4; ++rep) {
        const int col = rep * 32 + (tid >> 3);
        const int c8 = (tid & 7) * 8;
        uint4 v = *(const uint4*)&kpb[(size_t)(ct * 128 + col) * 64 + c8];
        *(uint4*)&Bsm[col * 72 + c8] = v;
    }
    __syncthreads();

    f32x4_t acc[4][4];
    #pragma unroll
    for (int i = 0; i < 4; ++i)
        #pragma unroll
        for (int j = 0; j < 4; ++j) acc[i][j] = f32x4_t{0.f, 0.f, 0.f, 0.f};

    #pragma unroll
    for (int s = 0; s < 2; ++s) {
        uint4 afr[4], bfr[4];
        #pragma unroll
        for (int i = 0; i < 4; ++i)
            afr[i] = *(const uint4*)&Asm[(wr * 64 + i * 16 + fr) * 72 + s * 32 + quad * 8];
        #pragma unroll
        for (int j = 0; j < 4; ++j)
            bfr[j] = *(const uint4*)&Bsm[(wc * 64 + j * 16 + fr) * 72 + s * 32 + quad * 8];
        #pragma unroll
        for (int i = 0; i < 4; ++i)
            #pragma unroll
            for (int j = 0; j < 4; ++j)
                acc[i][j] = __builtin_amdgcn_mfma_f32_16x16x32_bf16(
                    __builtin_bit_cast(bf16x8_t, afr[i]),
                    __builtin_bit_cast(bf16x8_t, bfr[j]),
                    acc[i][j], 0, 0, 0);
    }

    // epilogue: scale and pack 4 consecutive m per lane -> bmatT[b][col][m]
    #pragma unroll
    for (int i = 0; i < 4; ++i) {
        #pragma unroll
        for (int j = 0; j < 4; ++j) {
            const int colg = ct * 128 + wc * 64 + j * 16 + fr;
            ushort4 pk;
            {
                const int mb = wr * 64 + i * 16 + quad * 4;
                pk.x = f2bf(acc[i][j][0] * sfacl[wc * 128 + mb + 0]);
                pk.y = f2bf(acc[i][j][1] * sfacl[wc * 128 + mb + 1]);
                pk.z = f2bf(acc[i][j][2] * sfacl[wc * 128 + mb + 2]);
                pk.w = f2bf(acc[i][j][3] * sfacl[wc * 128 + mb + 3]);
                *(ushort4*)&bmatT[(size_t)(b * 512 + colg) * 1024 + m0 + mb] = pk;
            }
        }
    }
}

// K3: bf16 GEMM, BK=32, global_load_lds + XOR-4 k-group swizzle.
// grid 1024 = b(8) x rt(8) x [og(4) x kh(4)]; 4 waves; 128x128 tile, K/4=256.
// Each wave owns 32 rows x ALL 128 cols (2 A-frags x 8 B-frags): the t-reduction
// completes in registers -> no cross-wave red tile, no epilogue barriers.
// He2 partials stored in bf16 (halves epilogue write + k_fin read traffic).
__global__ __launch_bounds__(256) void k_gemm(const unsigned short* __restrict__ G,
                                              const unsigned short* __restrict__ bmatT,
                                              const float* __restrict__ escale,
                                              unsigned short* __restrict__ He2) {
    __shared__ unsigned short As[4096];   // [row(128)][k(32)] bf16, k-swizzled
    __shared__ unsigned short Bs[4096];   // [c'(128)=t*16+oo][k(32)] bf16, k-swizzled
    __shared__ float escT[1024];          // [t(8)][row(128)]

    const int b  = blockIdx.x & 7;        // XCD swizzle
    const int rt = (blockIdx.x >> 3) & 7;
    const int z  = blockIdx.x >> 6;       // 0..15
    const int og = z & 3;                 // channel group (16 ch)
    const int kh = z >> 2;                // K quarter
    const int n0 = rt * 128;
    const int kb = kh * 256;

    const int tid  = threadIdx.x;
    const int wave = tid >> 6, lane = tid & 63;

    {   // stage escale [8t][128 rows]
        const int t = tid >> 5, r4 = (tid & 31) * 4;
        *(float4*)&escT[t * 128 + r4] =
            *(const float4*)&escale[(size_t)(b * 8 + t) * 1024 + n0 + r4];
    }

    const unsigned short* gA = G + ((size_t)b << 20) + (size_t)n0 * 1024 + kb;
    const unsigned short* gB = bmatT + (size_t)(b * 512 + og * 16) * 1024 + kb;

    const int r16 = lane >> 2;            // row within 16-seg
    const int kq  = lane & 3;             // dest 16B k-group
    const int gsw = kq ^ (r16 & 3);       // swizzled source k-group
    const size_t gAoff = (size_t)r16 * 1024 + gsw * 8;

    f32x4_t acc[2][8];
    #pragma unroll
    for (int i = 0; i < 2; ++i)
        #pragma unroll
        for (int j = 0; j < 8; ++j) acc[i][j] = f32x4_t{0.f, 0.f, 0.f, 0.f};

    const int fr = lane & 15;             // fragment row/col part
    const int swoff = ((lane >> 4) ^ (fr & 3)) << 4;   // swizzled frag byte offset
    const int row_base = wave * 32;       // this wave's 32 output rows

    for (int kk = 0; kk < 8; ++kk) {
        const int k0 = kk * 32;
        __syncthreads();                  // all waves done with prev As/Bs
        #pragma unroll
        for (int i = 0; i < 2; ++i) {
            const int seg = wave * 2 + i;   // 16 rows (A) / one t: 16 cols (B)
            gld_lds16((char*)As + seg * 1024 + lane * 16,
                      gA + (size_t)(seg * 16) * 1024 + k0 + gAoff);
            gld_lds16((char*)Bs + seg * 1024 + lane * 16,
                      gB + (size_t)(seg * 64) * 1024 + (size_t)r16 * 1024 + k0 + gsw * 8);
        }
        __syncthreads();                  // DMA drained -> tiles visible
        uint4 afr0 = *(const uint4*)((const char*)As + (row_base + fr) * 64 + swoff);
        uint4 afr1 = *(const uint4*)((const char*)As + (row_base + 16 + fr) * 64 + swoff);
        #pragma unroll
        for (int j = 0; j < 8; ++j) {     // one B-frag live at a time (VGPR frugal)
            uint4 bfr = *(const uint4*)((const char*)Bs + (j * 16 + fr) * 64 + swoff);
            acc[0][j] = __builtin_amdgcn_mfma_f32_16x16x32_bf16(
                __builtin_bit_cast(bf16x8_t, afr0),
                __builtin_bit_cast(bf16x8_t, bfr), acc[0][j], 0, 0, 0);
            acc[1][j] = __builtin_amdgcn_mfma_f32_16x16x32_bf16(
                __builtin_bit_cast(bf16x8_t, afr1),
                __builtin_bit_cast(bf16x8_t, bfr), acc[1][j], 0, 0, 0);
        }
    }

    // epilogue: res[row][oo] = sum_t escT[t][row] * acc  — all in registers
    const int quad = lane >> 4, oo = lane & 15;
    unsigned short* dst = He2 + (size_t)kh * 524288
                              + (size_t)(b * 1024 + n0) * 64 + og * 16;
    #pragma unroll
    for (int i = 0; i < 2; ++i) {
        #pragma unroll
        for (int r = 0; r < 4; ++r) {
            const int row = row_base + i * 16 + quad * 4 + r;
            float s = 0.f;
            #pragma unroll
            for (int j = 0; j < 8; ++j)
                s += escT[j * 128 + row] * acc[i][j][r];
            dst[(size_t)row * 64 + oo] = f2bf(s);
        }
    }
}

// K4: out = sum of 4 bf16 He2 partials; fused BN sum/sumsq
__global__ __launch_bounds__(256) void k_fin(const unsigned short* __restrict__ He2,
                                             float* __restrict__ out,
                                             float* __restrict__ bns) {
    __shared__ float s1[16][64], s2[16][64];
    const int tid = threadIdx.x;
    float a0 = 0.f, a1 = 0.f, a2 = 0.f, a3 = 0.f;
    float q0 = 0.f, q1 = 0.f, q2 = 0.f, q3 = 0.f;
    #pragma unroll
    for (int it = 0; it < 2; ++it) {
        const size_t idx = (size_t)blockIdx.x * 512 + it * 256 + tid;  // ushort4 group
        float4 s = make_float4(0.f, 0.f, 0.f, 0.f);
        #pragma unroll
        for (int p = 0; p < 4; ++p) {
            ushort4 u = *(const ushort4*)(He2 + (size_t)p * 524288 + idx * 4);
            s.x += bf2f(u.x); s.y += bf2f(u.y); s.z += bf2f(u.z); s.w += bf2f(u.w);
        }
        ((float4*)out)[idx] = s;
        a0 += s.x; a1 += s.y; a2 += s.z; a3 += s.w;
        q0 += s.x * s.x; q1 += s.y * s.y; q2 += s.z * s.z; q3 += s.w * s.w;
    }
    const int g = tid >> 4, o4 = (tid & 15) * 4;
    *(float4*)&s1[g][o4] = make_float4(a0, a1, a2, a3);
    *(float4*)&s2[g][o4] = make_float4(q0, q1, q2, q3);
    __syncthreads();
    if (tid < 64) {
        float sa = 0.f, sb = 0.f;
        #pragma unroll
        for (int r = 0; r < 16; ++r) { sa += s1[r][tid]; sb += s2[r][tid]; }
        atomicAdd(&bns[tid], sa);
        atomicAdd(&bns[64 + tid], sb);
    }
}

// K5: in-place BN (training stats) + ReLU
__global__ __launch_bounds__(256) void k_bn(float* __restrict__ out,
                                            const float* __restrict__ bns,
                                            const float* __restrict__ gamma,
                                            const float* __restrict__ beta) {
    const int i = blockIdx.x * 256 + threadIdx.x;
    const int o4 = (i & 15) * 4;
    float4 x = ((float4*)out)[i];
    const float4 s  = *(const float4*)&bns[o4];
    const float4 s2 = *(const float4*)&bns[64 + o4];
    const float4 gm = *(const float4*)&gamma[o4];
    const float4 bt = *(const float4*)&beta[o4];
    const float invn = 1.f / 8192.f;
    float m, v, w;
    m = s.x * invn; v = s2.x * invn - m * m; w = __frsqrt_rn(v + BN_EPS) * gm.x;
    x.x = fmaxf((x.x - m) * w + bt.x, 0.f);
    m = s.y * invn; v = s2.y * invn - m * m; w = __frsqrt_rn(v + BN_EPS) * gm.y;
    x.y = fmaxf((x.y - m) * w + bt.y, 0.f);
    m = s.z * invn; v = s2.z * invn - m * m; w = __frsqrt_rn(v + BN_EPS) * gm.z;
    x.z = fmaxf((x.z - m) * w + bt.z, 0.f);
    m = s.w * invn; v = s2.w * invn - m * m; w = __frsqrt_rn(v + BN_EPS) * gm.w;
    x.w = fmaxf((x.w - m) * w + bt.w, 0.f);
    ((float4*)out)[i] = x;
}

extern "C" void kernel_launch(void* const* d_in, const int* in_sizes, int n_in,
                              void* d_out, int out_size, void* d_ws, size_t ws_size,
                              hipStream_t stream) {
    const float* points = (const float*)d_in[0];
    const float* trans  = (const float*)d_in[1];
    const float* funcs  = (const float*)d_in[2];
    const float* ktens  = (const float*)d_in[3];
    const float* gamma  = (const float*)d_in[4];
    const float* beta   = (const float*)d_in[5];
    float* out = (float*)d_out;

    float* ws      = (float*)d_ws;
    float* escale  = ws;                    // 65536 f
    float* bns     = escale + 65536;        // 128 f
    float* rowsum  = bns + 128;             // 8192 f
    unsigned short* He2   = (unsigned short*)(rowsum + 8192);   // 2097152 us (4 MB)
    unsigned short* kpb   = He2 + 2097152;                      // 32768 us
    unsigned short* G     = kpb + 32768;                        // 8388608 us
    unsigned short* bmatT = G + 8388608;                        // 4194304 us

    k_g<<<1152, 256, 0, stream>>>(points, ktens, G, rowsum, kpb, bns);
    k_prep<<<256, 256, 0, stream>>>(points, trans, funcs, kpb, rowsum, bmatT, escale);
    k_gemm<<<1024, 256, 0, stream>>>(G, bmatT, escale, He2);
    k_fin<<<256, 256, 0, stream>>>(He2, out, bns);
    k_bn<<<512, 256, 0, stream>>>(out, bns, gamma, beta);
}